// Round 15
// baseline (725.650 us; speedup 1.0000x reference)
//
#include <hip/hip_runtime.h>
#include <hip/hip_bf16.h>
#include <stdint.h>

// ---------- helpers ----------
#define AS1(p) ((const __attribute__((address_space(1))) void*)(p))
#define AS3(p) ((__attribute__((address_space(3))) void*)(p))

typedef __bf16 bf16x8 __attribute__((ext_vector_type(8)));
typedef __bf16 bf16x4 __attribute__((ext_vector_type(4)));
typedef float f32x4 __attribute__((ext_vector_type(4)));
typedef unsigned short u16;

#define MFMA(a, b, cc) __builtin_amdgcn_mfma_f32_16x16x32_bf16(a, b, cc, 0, 0, 0)
// Drain outstanding DS ops (reads included) BEFORE a barrier (r8 lesson).
#define DS_DRAIN() asm volatile("s_waitcnt lgkmcnt(0)" ::: "memory")

__device__ __forceinline__ u16 f2bf(float f) {
  unsigned u = __builtin_bit_cast(unsigned, f);
  u = (u + 0x7FFFu + ((u >> 16) & 1u)) >> 16;   // RNE
  return (u16)u;
}

// ---------- constants ----------
// B=16 L=4096 N=64 D=64 H=4 WAVE=16 T=256 DFF=256 DH=16 TOPK=16

// ---------- k_wprep: weight transposes + (block 656) cosine-topk bias ----------
__global__ void k_wprep(const float* __restrict__ Wq, const float* __restrict__ Wk,
                        const float* __restrict__ Wv, const float* __restrict__ Wo,
                        const float* __restrict__ W1, const float* __restrict__ W2,
                        const float* __restrict__ conv_w, const float* __restrict__ conv_b,
                        const float* __restrict__ emb,
                        u16* __restrict__ WqT, u16* __restrict__ WkT,
                        u16* __restrict__ WvT, u16* __restrict__ WoT,
                        u16* __restrict__ W1T, u16* __restrict__ W2T,
                        float* __restrict__ cwT, float* __restrict__ cbT,
                        float* __restrict__ bias) {
  __shared__ float sh[8320];   // e[4096] | nrm[64] | cosr[64*65] (bias block only)
  int tid = threadIdx.x;
  if (blockIdx.x == 656) {
    float* e = sh; float* nrm = sh + 4096; float* cosr = sh + 4160;
    for (int idx = tid; idx < 4096; idx += 256) e[idx] = emb[idx];
    __syncthreads();
    if (tid < 64) {
      float s = 0.f;
      for (int j = 0; j < 64; j++) { float v = e[tid * 64 + j]; s += v * v; }
      nrm[tid] = sqrtf(s);
    }
    __syncthreads();
    if (tid < 64) {
      for (int jj = 0; jj < 64; jj++) {
        float d = 0.f;
        for (int kk = 0; kk < 64; kk++) d += e[tid * 64 + kk] * e[jj * 64 + kk];
        cosr[tid * 65 + jj] = d / (nrm[tid] * nrm[jj]);
      }
      unsigned long long sel = 0ull;
      for (int it = 0; it < 16; it++) {
        float best = -1e30f; int bi = 0;
        for (int j = 0; j < 64; j++) {
          if ((sel >> j) & 1ull) continue;
          float cv = cosr[tid * 65 + j];
          if (cv > best) { best = cv; bi = j; }
        }
        sel |= (1ull << bi);
      }
      for (int j = 0; j < 64; j++)
        bias[tid * 64 + j] = ((sel >> j) & 1ull) ? 0.0f : -1e9f;
    }
    return;
  }
  int e = blockIdx.x * 256 + tid;   // 167936 total
  if (e < 98304) {
    int l = e / 49152, r = e % 49152;
    if (r < 16384) {
      int mat = r >> 12, i = r & 4095, n = i >> 6, k = i & 63;
      const float* W = mat == 0 ? Wq : mat == 1 ? Wk : mat == 2 ? Wv : Wo;
      u16* WT = mat == 0 ? WqT : mat == 1 ? WkT : mat == 2 ? WvT : WoT;
      WT[l * 4096 + i] = f2bf(W[l * 4096 + k * 64 + n]);
    } else if (r < 32768) {
      int i = r - 16384, n = i >> 6, k = i & 63;
      W1T[l * 16384 + i] = f2bf(W1[l * 16384 + k * 256 + n]);
    } else {
      int i = r - 32768, n = i >> 8, k = i & 255;
      W2T[l * 16384 + i] = f2bf(W2[l * 16384 + k * 64 + n]);
    }
  } else if (e < 163840) {
    int i = e - 98304;                       // cwT[(n*16+w)*64+d] = conv_w[(d*64+n)*16+w]
    int d = i & 63, w = (i >> 6) & 15, n = i >> 10;
    cwT[i] = conv_w[(d * 64 + n) * 16 + w];
  } else {
    int i = e - 163840;                      // cbT[n*64+d] = conv_b[d*64+n]
    int d = i & 63, n = i >> 6;
    cbT[i] = conv_b[d * 64 + n];
  }
}

// ---------- k_conv: coalesced via transposed weights (cwT[n][w][d], cbT[n][d]) ----------
__global__ void k_conv(const float* __restrict__ x, const float* __restrict__ cwT,
                       const float* __restrict__ cbT, float* __restrict__ h) {
  int bt = blockIdx.x;
  __shared__ float xs[1024];
  int tid = threadIdx.x;
  ((f32x4*)xs)[tid] = ((const f32x4*)(x + ((size_t)bt << 10)))[tid];
  __syncthreads();
  int d = tid & 63, n0 = (tid >> 6) << 4;
  float xv[16];
  #pragma unroll
  for (int w = 0; w < 16; w++) xv[w] = xs[w * 64 + d];
  #pragma unroll
  for (int i = 0; i < 16; i++) {
    int n = n0 + i;
    float acc = cbT[n * 64 + d];
    const float* wp = &cwT[n * 1024 + d];   // lane d -> consecutive addresses
    #pragma unroll
    for (int w = 0; w < 16; w++) acc += xv[w] * wp[w * 64];
    h[((size_t)bt << 12) + n * 64 + d] = acc;
  }
}

// ---------- k_layer2: fused MFMA transformer layer, PERSISTENT blocks ----------
// r15: grid 512 (2 blocks/CU, all resident); each block loops 8 tokens with
// ALL weight/bias fragments prefetched ONCE (resident in VGPRs across tokens).
// Per-token phase/barrier structure identical to r9-r14 (race-audited).
// LDS 70656 B (dead pb buffer removed) -> 2 blocks/CU.
__global__ __launch_bounds__(256, 2) void k_layer2(
    float* __restrict__ hbuf, const float* __restrict__ emb, const float* __restrict__ bias,
    const u16* __restrict__ WqT, const u16* __restrict__ WkT,
    const u16* __restrict__ WvT, const u16* __restrict__ WoT,
    const u16* __restrict__ W1T, const u16* __restrict__ W2T,
    const float* __restrict__ bq, const float* __restrict__ bk,
    const float* __restrict__ bv, const float* __restrict__ bo,
    const float* __restrict__ ln1g, const float* __restrict__ ln1b,
    const float* __restrict__ ln2g, const float* __restrict__ ln2b,
    const float* __restrict__ b1, const float* __restrict__ b2,
    const float* __restrict__ r1p, const float* __restrict__ r2p,
    u16* __restrict__ aout) {
  __shared__ __align__(16) unsigned char smem[70656];
  float* hres = (float*)smem;                 // [64][68] f32
  __bf16* act = (__bf16*)(smem + 17408);      // [64][72]
  __bf16* qb  = (__bf16*)(smem + 26624);      // [64][136] (per-head 32-wide, hi 16 zero)
  __bf16* kb  = (__bf16*)(smem + 44032);      // [64][136]
  __bf16* vtb = (__bf16*)(smem + 61440);      // [64][72]  V^T [d][node]
  __bf16* ps  = (__bf16*)(smem + 26624);      // [64][264] P, overlays qb+kb
  __bf16* gb  = (__bf16*)(smem + 26624);      // [64][264] FFN hidden, overlays qb+kb

  const int tid = threadIdx.x;
  const int w = tid >> 6, lane = tid & 63;
  const int g = lane >> 4, c = lane & 15;
  const float r1 = *r1p, r2 = *r2p;

  // --- one-time prefetch: ALL weights + biases resident across the token loop ---
  const int wrow = (w * 16 + c) * 64 + g * 8;
  bf16x8 wq0 = *(const bf16x8*)&WqT[wrow];
  bf16x8 wq1 = *(const bf16x8*)&WqT[wrow + 32];
  bf16x8 wk0 = *(const bf16x8*)&WkT[wrow];
  bf16x8 wk1 = *(const bf16x8*)&WkT[wrow + 32];
  bf16x8 wv0 = *(const bf16x8*)&WvT[wrow];
  bf16x8 wv1 = *(const bf16x8*)&WvT[wrow + 32];
  bf16x8 wo0 = *(const bf16x8*)&WoT[wrow];
  bf16x8 wo1 = *(const bf16x8*)&WoT[wrow + 32];
  f32x4 bq4 = *(const f32x4*)&bq[w * 16 + g * 4];
  f32x4 bk4 = *(const f32x4*)&bk[w * 16 + g * 4];
  f32x4 bo4 = *(const f32x4*)&bo[w * 16 + g * 4];
  f32x4 b24 = *(const f32x4*)&b2[w * 16 + g * 4];
  float bvv = bv[w * 16 + c];
  bf16x8 w1f[4][2];
  f32x4 b14[4];
  #pragma unroll
  for (int ft = 0; ft < 4; ft++) {
    int ffb = (w << 6) + (ft << 4);
    w1f[ft][0] = *(const bf16x8*)&W1T[(ffb + c) * 64 + g * 8];
    w1f[ft][1] = *(const bf16x8*)&W1T[(ffb + c) * 64 + 32 + g * 8];
    b14[ft] = *(const f32x4*)&b1[ffb + g * 4];
  }
  bf16x8 w2f[8];
  #pragma unroll
  for (int ks = 0; ks < 8; ks++)
    w2f[ks] = *(const bf16x8*)&W2T[(w * 16 + c) * 256 + ks * 32 + g * 8];
  float bias_r[4][4];
  #pragma unroll
  for (int jj = 0; jj < 4; jj++)
    #pragma unroll
    for (int ct = 0; ct < 4; ct++)
      bias_r[jj][ct] = bias[(w * 16 + g * 4 + jj) * 64 + ct * 16 + c];

  bf16x8 af[4][2];
  auto load_af_act = [&]() {
    #pragma unroll
    for (int rt = 0; rt < 4; rt++)
      #pragma unroll
      for (int ks = 0; ks < 2; ks++)
        af[rt][ks] = *(const bf16x8*)&act[(rt * 16 + c) * 72 + ks * 32 + g * 8];
  };

  for (int it = 0; it < 8; ++it) {
    const int bt = (blockIdx.x << 3) | it;
    const size_t base = (size_t)bt << 12;

    // phase 1: load h, hin = h+emb -> act(bf16); zero qb/kb (padding lanes)
    #pragma unroll
    for (int i = 0; i < 4; i++) {
      int v = tid + (i << 8);
      f32x4 hv = ((const f32x4*)(hbuf + base))[v];
      f32x4 ev = ((const f32x4*)emb)[v];
      int n = v >> 4, d = (v & 15) << 2;
      *(f32x4*)&hres[n * 68 + d] = hv;
      bf16x4 u;
      u[0] = (__bf16)(hv[0] + ev[0]); u[1] = (__bf16)(hv[1] + ev[1]);
      u[2] = (__bf16)(hv[2] + ev[2]); u[3] = (__bf16)(hv[3] + ev[3]);
      *(bf16x4*)&act[n * 72 + d] = u;
    }
    for (int i = tid; i < 2176; i += 256) {
      f32x4 z; z[0] = 0.f; z[1] = 0.f; z[2] = 0.f; z[3] = 0.f;
      ((f32x4*)(smem + 26624))[i] = z;
    }
    __syncthreads();   // bar1

    // phase 2: QKV (q/k operand-swapped -> packed stores; v -> vtb[d][n])
    load_af_act();
    {
      #pragma unroll
      for (int nt = 0; nt < 4; nt++) {
        f32x4 a; a[0]=0.f; a[1]=0.f; a[2]=0.f; a[3]=0.f;
        a = MFMA(wq0, af[nt][0], a);
        a = MFMA(wq1, af[nt][1], a);
        bf16x4 st;
        #pragma unroll
        for (int jj = 0; jj < 4; jj++) st[jj] = (__bf16)(a[jj] + bq4[jj]);
        *(bf16x4*)&qb[(nt * 16 + c) * 136 + w * 32 + g * 4] = st;
      }
      #pragma unroll
      for (int nt = 0; nt < 4; nt++) {
        f32x4 a; a[0]=0.f; a[1]=0.f; a[2]=0.f; a[3]=0.f;
        a = MFMA(wk0, af[nt][0], a);
        a = MFMA(wk1, af[nt][1], a);
        bf16x4 st;
        #pragma unroll
        for (int jj = 0; jj < 4; jj++) st[jj] = (__bf16)(a[jj] + bk4[jj]);
        *(bf16x4*)&kb[(nt * 16 + c) * 136 + w * 32 + g * 4] = st;
      }
      #pragma unroll
      for (int nt = 0; nt < 4; nt++) {
        f32x4 a; a[0]=0.f; a[1]=0.f; a[2]=0.f; a[3]=0.f;
        a = MFMA(af[nt][0], wv0, a);
        a = MFMA(af[nt][1], wv1, a);
        bf16x4 st;
        #pragma unroll
        for (int jj = 0; jj < 4; jj++) st[jj] = (__bf16)(a[jj] + bvv);
        *(bf16x4*)&vtb[(w * 16 + c) * 72 + nt * 16 + g * 4] = st;
      }
    }
    __syncthreads();   // bar2

    // phase 3: attention (row-split: wave w owns query rows 16w..16w+15)
    {
      // Stage A: all 4 heads' QK^T into registers
      f32x4 sc4[4][4];   // [head][ct]
      #pragma unroll
      for (int h = 0; h < 4; h++) {
        bf16x8 aq = *(const bf16x8*)&qb[(w * 16 + c) * 136 + h * 32 + g * 8];
        #pragma unroll
        for (int ct = 0; ct < 4; ct++) {
          bf16x8 bk8 = *(const bf16x8*)&kb[(ct * 16 + c) * 136 + h * 32 + g * 8];
          f32x4 z0; z0[0]=0.f; z0[1]=0.f; z0[2]=0.f; z0[3]=0.f;
          sc4[h][ct] = MFMA(aq, bk8, z0);
        }
      }
      // Stage B (registers only): softmax consumes sc4 BEFORE the barrier
      #pragma unroll
      for (int h = 0; h < 4; h++) {
        #pragma unroll
        for (int jj = 0; jj < 4; jj++) {
          float s0 = sc4[h][0][jj] * 0.25f + bias_r[jj][0];
          float s1 = sc4[h][1][jj] * 0.25f + bias_r[jj][1];
          float s2 = sc4[h][2][jj] * 0.25f + bias_r[jj][2];
          float s3 = sc4[h][3][jj] * 0.25f + bias_r[jj][3];
          float m = fmaxf(fmaxf(s0, s1), fmaxf(s2, s3));
          m = fmaxf(m, __shfl_xor(m, 1)); m = fmaxf(m, __shfl_xor(m, 2));
          m = fmaxf(m, __shfl_xor(m, 4)); m = fmaxf(m, __shfl_xor(m, 8));
          float e0 = __expf(s0 - m), e1 = __expf(s1 - m), e2 = __expf(s2 - m), e3 = __expf(s3 - m);
          float sum = e0 + e1 + e2 + e3;
          sum += __shfl_xor(sum, 1); sum += __shfl_xor(sum, 2);
          sum += __shfl_xor(sum, 4); sum += __shfl_xor(sum, 8);
          float inv = __builtin_amdgcn_rcpf(sum);
          sc4[h][0][jj] = e0 * inv;
          sc4[h][1][jj] = e1 * inv;
          sc4[h][2][jj] = e2 * inv;
          sc4[h][3][jj] = e3 * inv;
        }
      }
      DS_DRAIN();        // no qb/kb read may be in flight across the barrier
      __syncthreads();   // qb/kb region now dead -> becomes ps
      // Stage B'': store P (bf16)
      #pragma unroll
      for (int h = 0; h < 4; h++) {
        #pragma unroll
        for (int jj = 0; jj < 4; jj++) {
          int prow = w * 16 + g * 4 + jj;
          ps[prow * 264 + h * 64 +  0 + c] = (__bf16)sc4[h][0][jj];
          ps[prow * 264 + h * 64 + 16 + c] = (__bf16)sc4[h][1][jj];
          ps[prow * 264 + h * 64 + 32 + c] = (__bf16)sc4[h][2][jj];
          ps[prow * 264 + h * 64 + 48 + c] = (__bf16)sc4[h][3][jj];
        }
      }
      __syncthreads();   // P visible
      // Stage C: PV operand-swapped -> packed bf16x4 act stores
      #pragma unroll
      for (int h = 0; h < 4; h++) {
        f32x4 oacc; oacc[0]=0.f; oacc[1]=0.f; oacc[2]=0.f; oacc[3]=0.f;
        #pragma unroll
        for (int ks = 0; ks < 2; ks++) {
          bf16x8 ap  = *(const bf16x8*)&ps[(w * 16 + c) * 264 + h * 64 + ks * 32 + g * 8];
          bf16x8 bv8 = *(const bf16x8*)&vtb[(h * 16 + c) * 72 + ks * 32 + g * 8];
          oacc = MFMA(bv8, ap, oacc);
        }
        bf16x4 st;
        #pragma unroll
        for (int jj = 0; jj < 4; jj++) st[jj] = (__bf16)oacc[jj];
        *(bf16x4*)&act[(w * 16 + c) * 72 + h * 16 + g * 4] = st;
      }
    }
    __syncthreads();   // bar3

    // phase 4: proj + residual
    load_af_act();
    {
      #pragma unroll
      for (int nt = 0; nt < 4; nt++) {
        f32x4 a; a[0]=0.f; a[1]=0.f; a[2]=0.f; a[3]=0.f;
        a = MFMA(wo0, af[nt][0], a);
        a = MFMA(wo1, af[nt][1], a);
        float* hp = &hres[(nt * 16 + c) * 68 + w * 16 + g * 4];
        f32x4 hv = *(f32x4*)hp;
        #pragma unroll
        for (int jj = 0; jj < 4; jj++) hv[jj] += r1 * (a[jj] + bo4[jj]);
        *(f32x4*)hp = hv;
      }
    }
    __syncthreads();   // bar4

    // phase 5: LN1 -> act AND hres
    {
      int row = w * 16 + (lane >> 2), c0 = (lane & 3) << 4;
      float s = 0.f, s2 = 0.f;
      #pragma unroll
      for (int jv = 0; jv < 4; jv++) {
        f32x4 v = *(const f32x4*)&hres[row * 68 + c0 + jv * 4];
        s += v[0] + v[1] + v[2] + v[3];
        s2 += v[0]*v[0] + v[1]*v[1] + v[2]*v[2] + v[3]*v[3];
      }
      s += __shfl_xor(s, 1);  s += __shfl_xor(s, 2);
      s2 += __shfl_xor(s2, 1); s2 += __shfl_xor(s2, 2);
      float mean = s * 0.015625f, var = s2 * 0.015625f - mean * mean;
      float rstd = rsqrtf(var + 1e-5f);
      #pragma unroll
      for (int jv = 0; jv < 4; jv++) {
        f32x4 v = *(const f32x4*)&hres[row * 68 + c0 + jv * 4];
        f32x4 gg = *(const f32x4*)&ln1g[c0 + jv * 4];
        f32x4 bb = *(const f32x4*)&ln1b[c0 + jv * 4];
        f32x4 o; bf16x4 ob;
        #pragma unroll
        for (int e = 0; e < 4; e++) {
          o[e] = (v[e] - mean) * rstd * gg[e] + bb[e];
          ob[e] = (__bf16)o[e];
        }
        *(f32x4*)&hres[row * 68 + c0 + jv * 4] = o;
        *(bf16x4*)&act[row * 72 + c0 + jv * 4] = ob;
      }
    }
    __syncthreads();   // bar5

    // phase 6: FFN1 (weights resident in w1f/b14)
    load_af_act();
    #pragma unroll
    for (int ft = 0; ft < 4; ft++) {
      int ffb = (w << 6) + (ft << 4);
      #pragma unroll
      for (int nt = 0; nt < 4; nt++) {
        f32x4 a; a[0]=0.f; a[1]=0.f; a[2]=0.f; a[3]=0.f;
        a = MFMA(w1f[ft][0], af[nt][0], a);
        a = MFMA(w1f[ft][1], af[nt][1], a);
        bf16x4 st;
        #pragma unroll
        for (int jj = 0; jj < 4; jj++) {
          float xg = a[jj] + b14[ft][jj];
          float e = __expf(1.5957691216057308f * (xg + 0.044715f * xg * xg * xg));
          float r = __builtin_amdgcn_rcpf(1.f + e);
          st[jj] = (__bf16)(xg - xg * r);
        }
        *(bf16x4*)&gb[(nt * 16 + c) * 264 + ffb + g * 4] = st;
      }
    }
    __syncthreads();   // bar6

    // phase 7: FFN2 + residual (weights resident in w2f)
    {
      f32x4 a2[4];
      #pragma unroll
      for (int nt = 0; nt < 4; nt++) { a2[nt][0]=0.f; a2[nt][1]=0.f; a2[nt][2]=0.f; a2[nt][3]=0.f; }
      #pragma unroll
      for (int ks = 0; ks < 8; ks++) {
        #pragma unroll
        for (int nt = 0; nt < 4; nt++) {
          bf16x8 ag = *(const bf16x8*)&gb[(nt * 16 + c) * 264 + ks * 32 + g * 8];
          a2[nt] = MFMA(w2f[ks], ag, a2[nt]);
        }
      }
      #pragma unroll
      for (int nt = 0; nt < 4; nt++) {
        float* hp = &hres[(nt * 16 + c) * 68 + w * 16 + g * 4];
        f32x4 hv = *(f32x4*)hp;
        #pragma unroll
        for (int jj = 0; jj < 4; jj++) hv[jj] += r2 * (a2[nt][jj] + b24[jj]);
        *(f32x4*)hp = hv;
      }
    }
    __syncthreads();   // bar7

    // phase 8: LN2 -> hbuf (fp32) or fused packA -> aout (bf16 GEMM A)
    {
      int row = w * 16 + (lane >> 2), c0 = (lane & 3) << 4;
      float s = 0.f, s2 = 0.f;
      #pragma unroll
      for (int jv = 0; jv < 4; jv++) {
        f32x4 v = *(const f32x4*)&hres[row * 68 + c0 + jv * 4];
        s += v[0] + v[1] + v[2] + v[3];
        s2 += v[0]*v[0] + v[1]*v[1] + v[2]*v[2] + v[3]*v[3];
      }
      s += __shfl_xor(s, 1);  s += __shfl_xor(s, 2);
      s2 += __shfl_xor(s2, 1); s2 += __shfl_xor(s2, 2);
      float mean = s * 0.015625f, var = s2 * 0.015625f - mean * mean;
      float rstd = rsqrtf(var + 1e-5f);
      if (aout) {
        int b = bt >> 8, t = bt & 255;
        __bf16* ao = (__bf16*)aout + (((size_t)(b * 64 + row)) << 14) + (t << 6) + c0;
        #pragma unroll
        for (int jv = 0; jv < 4; jv++) {
          f32x4 v = *(const f32x4*)&hres[row * 68 + c0 + jv * 4];
          f32x4 gg = *(const f32x4*)&ln2g[c0 + jv * 4];
          f32x4 bb = *(const f32x4*)&ln2b[c0 + jv * 4];
          bf16x4 us;
          #pragma unroll
          for (int e = 0; e < 4; e++)
            us[e] = (__bf16)((v[e] - mean) * rstd * gg[e] + bb[e]);
          *(bf16x4*)&ao[jv * 4] = us;
        }
      } else {
        #pragma unroll
        for (int jv = 0; jv < 4; jv++) {
          f32x4 v = *(const f32x4*)&hres[row * 68 + c0 + jv * 4];
          f32x4 gg = *(const f32x4*)&ln2g[c0 + jv * 4];
          f32x4 bb = *(const f32x4*)&ln2b[c0 + jv * 4];
          f32x4 o;
          #pragma unroll
          for (int e = 0; e < 4; e++)
            o[e] = (v[e] - mean) * rstd * gg[e] + bb[e];
          *(f32x4*)&hbuf[base + row * 64 + c0 + jv * 4] = o;
        }
      }
    }
    // loop-end fence: next token's phase 1 overwrites hres/act/qkb; all this
    // token's LDS reads were consumed above (r9 recipe).
    DS_DRAIN();
    __syncthreads();
  }
}

// ---------- k_transpose: lin_w [16384][4096] f32 -> wt [4096][16384] bf16 ----------
__global__ __launch_bounds__(256) void k_transpose(const float* __restrict__ w,
                                                   u16* __restrict__ wt) {
  __shared__ u16 tb[128 * 256];   // 64 KB
  const int bn = blockIdx.x & 15;   // 16 n-tiles of 256
  const int bk = blockIdx.x >> 4;   // 128 k-tiles of 128
  const int tid = threadIdx.x;
  #pragma unroll
  for (int i = 0; i < 32; i++) {
    int chunk = i * 256 + tid;
    int row = chunk >> 6, cq = chunk & 63;
    f32x4 v = *(const f32x4*)&w[((size_t)(bk * 128 + row)) * 4096 + bn * 256 + cq * 4];
    ushort4 u;
    u.x = f2bf(v[0]); u.y = f2bf(v[1]); u.z = f2bf(v[2]); u.w = f2bf(v[3]);
    int pc = cq ^ ((row >> 2) & 15);
    *(ushort4*)&tb[row * 256 + pc * 4] = u;
  }
  __syncthreads();
  #pragma unroll
  for (int i = 0; i < 32; i++) {
    int chunk = i * 256 + tid;
    int n = chunk >> 5, kq = chunk & 31;
    int pc = (n >> 2) ^ (kq & 15);
    int nl = n & 3;
    ushort4 u;
    u.x = tb[(kq * 4 + 0) * 256 + pc * 4 + nl];
    u.y = tb[(kq * 4 + 1) * 256 + pc * 4 + nl];
    u.z = tb[(kq * 4 + 2) * 256 + pc * 4 + nl];
    u.w = tb[(kq * 4 + 3) * 256 + pc * 4 + nl];
    *(ushort4*)&wt[((size_t)(bn * 256 + n)) * 16384 + bk * 128 + kq * 4] = u;
  }
}

// ---------- k_gemm3: 256x128 tile, K-split x4, 512 blocks, XOR-swizzled LDS ----------
__global__ __launch_bounds__(256, 2) void k_gemm3(const u16* __restrict__ A,
                                                  const u16* __restrict__ Bt,
                                                  float* __restrict__ P) {
  __shared__ u16 As[256 * 64];   // 32 KB
  __shared__ u16 Bs[128 * 64];   // 16 KB
  const int tid = threadIdx.x;
  const int lane = tid & 63;
  const int wv = tid >> 6;
  const int bid = ((blockIdx.x & 7) << 6) | (blockIdx.x >> 3);
  const int split = bid >> 7;
  const int tile = bid & 127;
  const int bm = tile >> 5, bn = tile & 31;
  const int m0 = bm << 8, n0 = bn << 7;
  f32x4 acc[4][8];
  #pragma unroll
  for (int i = 0; i < 4; i++)
    #pragma unroll
    for (int j = 0; j < 8; j++) { acc[i][j][0]=0.f; acc[i][j][1]=0.f; acc[i][j][2]=0.f; acc[i][j][3]=0.f; }

  const int r15 = lane & 15;
  const int g = lane >> 4;
  const u16* abase = A  + ((size_t)m0 << 14) + (split << 12);
  const u16* bbase = Bt + ((size_t)n0 << 14) + (split << 12);

  for (int kt = 0; kt < 64; kt++) {
    const u16* ab = abase + (kt << 6);
    const u16* bb = bbase + (kt << 6);
    #pragma unroll
    for (int j = 0; j < 8; j++) {
      int cix = (j << 8) + tid;
      int row = cix >> 3;
      int sc  = (cix & 7) ^ (row & 7);
      int off = (row << 14) + (sc << 3);
      __builtin_amdgcn_global_load_lds(AS1(ab + off), AS3(&As[(j << 11) + (wv << 9)]), 16, 0, 0);
    }
    #pragma unroll
    for (int j = 0; j < 4; j++) {
      int cix = (j << 8) + tid;
      int row = cix >> 3;
      int sc  = (cix & 7) ^ (row & 7);
      int off = (row << 14) + (sc << 3);
      __builtin_amdgcn_global_load_lds(AS1(bb + off), AS3(&Bs[(j << 11) + (wv << 9)]), 16, 0, 0);
    }
    __syncthreads();
    #pragma unroll
    for (int ks = 0; ks < 2; ks++) {
      const int pc = ((ks << 2) + g) ^ (r15 & 7);
      bf16x8 af2[4], bfr[8];
      #pragma unroll
      for (int mi = 0; mi < 4; mi++)
        af2[mi] = *(const bf16x8*)&As[((wv << 6) + mi * 16 + r15) * 64 + (pc << 3)];
      #pragma unroll
      for (int ni = 0; ni < 8; ni++)
        bfr[ni] = *(const bf16x8*)&Bs[(ni * 16 + r15) * 64 + (pc << 3)];
      #pragma unroll
      for (int mi = 0; mi < 4; mi++)
        #pragma unroll
        for (int ni = 0; ni < 8; ni++)
          acc[mi][ni] = MFMA(af2[mi], bfr[ni], acc[mi][ni]);
    }
    __syncthreads();
  }

  float* Pp = P + ((size_t)split << 22);
  #pragma unroll
  for (int mi = 0; mi < 4; mi++) {
    #pragma unroll
    for (int ni = 0; ni < 8; ni++) {
      int col = n0 + ni * 16 + r15;
      #pragma unroll
      for (int j = 0; j < 4; j++) {
        int row = m0 + (wv << 6) + mi * 16 + (g << 2) + j;
        Pp[((size_t)row << 12) + col] = acc[mi][ni][j];
      }
    }
  }
}

// ---------- k_reduce: sum 4 K-splits + bias, transpose to out[b,l,n] ----------
__global__ void k_reduce(const float* __restrict__ P, const float* __restrict__ lin_b,
                         float* __restrict__ out) {
  __shared__ float tile[64][65];
  int b = blockIdx.x >> 6, lt = blockIdx.x & 63;
  int tid = threadIdx.x, c = tid & 63, r0 = tid >> 6;
  const float* Pb = P + (((size_t)b * 64) << 12) + (lt << 6);
  #pragma unroll
  for (int i = 0; i < 16; i++) {
    int node = r0 + i * 4;
    size_t off = ((size_t)node << 12) + c;
    float s = Pb[off] + Pb[off + 4194304] + Pb[off + 8388608] + Pb[off + 12582912];
    tile[node][c] = s;
  }
  __syncthreads();
  #pragma unroll
  for (int i = 0; i < 16; i++) {
    int lo = r0 + i * 4;
    out[((size_t)(b * 4096 + lt * 64 + lo)) * 64 + c] = tile[c][lo] + lin_b[lt * 64 + lo];
  }
}

// ---------- launch ----------
extern "C" void kernel_launch(void* const* d_in, const int* in_sizes, int n_in,
                              void* d_out, int out_size, void* d_ws, size_t ws_size,
                              hipStream_t stream) {
  const float* x      = (const float*)d_in[0];
  const float* emb    = (const float*)d_in[1];
  const float* conv_w = (const float*)d_in[2];
  const float* conv_b = (const float*)d_in[3];
  const float* Wq = (const float*)d_in[4],  *bq = (const float*)d_in[5];
  const float* Wk = (const float*)d_in[6],  *bk = (const float*)d_in[7];
  const float* Wv = (const float*)d_in[8],  *bv = (const float*)d_in[9];
  const float* Wo = (const float*)d_in[10], *bo = (const float*)d_in[11];
  const float* ln1g = (const float*)d_in[12], *ln1b = (const float*)d_in[13];
  const float* ln2g = (const float*)d_in[14], *ln2b = (const float*)d_in[15];
  const float* W1 = (const float*)d_in[16], *b1 = (const float*)d_in[17];
  const float* W2 = (const float*)d_in[18], *b2 = (const float*)d_in[19];
  const float* res1 = (const float*)d_in[20], *res2 = (const float*)d_in[21];
  const float* lin_w = (const float*)d_in[22], *lin_b = (const float*)d_in[23];
  float* out = (float*)d_out;

  char* ws = (char*)d_ws;
  float* bias   = (float*)ws;                                        //    16,384 B
  float* hbuf   = (float*)(ws + 16384);                              // 67,108,864 B (layers)
  float* Ppart  = hbuf;                                              // overlay: GEMM partials (after layers)
  u16*   wt     = (u16*)(ws + 16384 + 67108864);                     // 134,217,728 B
  u16*   Abf    = (u16*)(ws + 16384 + 67108864 + 134217728);         // 33,554,432 B
  u16*   WTb    = (u16*)(ws + 16384 + 67108864 + 134217728 + 33554432); // 196,608 B
  u16* WqT = WTb;                 // 8192 elems (2 layers)
  u16* WkT = WTb + 8192;
  u16* WvT = WTb + 16384;
  u16* WoT = WTb + 24576;
  u16* W1T = WTb + 32768;         // 32768 elems
  u16* W2T = WTb + 65536;         // 32768 elems
  // conv transposed weights live in the dead PREFIX of Abf (k_conv runs before
  // the layers; layer-1's fused packA overwrites this region afterwards).
  float* cwT = (float*)Abf;       // 65536 f32 = 262,144 B
  float* cbT = cwT + 65536;       //  4096 f32 =  16,384 B

  k_wprep<<<657, 256, 0, stream>>>(Wq, Wk, Wv, Wo, W1, W2, conv_w, conv_b, emb,
                                   WqT, WkT, WvT, WoT, W1T, W2T, cwT, cbT, bias);
  k_conv<<<4096, 256, 0, stream>>>(x, cwT, cbT, hbuf);
  k_transpose<<<2048, 256, 0, stream>>>(lin_w, wt);
  for (int l = 0; l < 2; l++)
    k_layer2<<<512, 256, 0, stream>>>(hbuf, emb, bias,
        WqT + l * 4096, WkT + l * 4096, WvT + l * 4096, WoT + l * 4096,
        W1T + l * 16384, W2T + l * 16384,
        bq + l * 64, bk + l * 64, bv + l * 64, bo + l * 64,
        ln1g + l * 64, ln1b + l * 64, ln2g + l * 64, ln2b + l * 64,
        b1 + l * 256, b2 + l * 64, res1 + l, res2 + l,
        (l == 1) ? Abf : (u16*)nullptr);
  k_gemm3<<<512, 256, 0, stream>>>(Abf, wt, Ppart);
  k_reduce<<<1024, 256, 0, stream>>>(Ppart, lin_b, out);
}

// Round 16
// 644.850 us; speedup vs baseline: 1.1253x; 1.1253x over previous
//
#include <hip/hip_runtime.h>
#include <hip/hip_bf16.h>
#include <stdint.h>

// ---------- helpers ----------
#define AS1(p) ((const __attribute__((address_space(1))) void*)(p))
#define AS3(p) ((__attribute__((address_space(3))) void*)(p))

typedef __bf16 bf16x8 __attribute__((ext_vector_type(8)));
typedef __bf16 bf16x4 __attribute__((ext_vector_type(4)));
typedef float f32x4 __attribute__((ext_vector_type(4)));
typedef unsigned short u16;

#define MFMA(a, b, cc) __builtin_amdgcn_mfma_f32_16x16x32_bf16(a, b, cc, 0, 0, 0)
// Drain outstanding DS ops (reads included) BEFORE a barrier (r8 lesson).
#define DS_DRAIN() asm volatile("s_waitcnt lgkmcnt(0)" ::: "memory")

__device__ __forceinline__ u16 f2bf(float f) {
  unsigned u = __builtin_bit_cast(unsigned, f);
  u = (u + 0x7FFFu + ((u >> 16) & 1u)) >> 16;   // RNE
  return (u16)u;
}

// ---------- constants ----------
// B=16 L=4096 N=64 D=64 H=4 WAVE=16 T=256 DFF=256 DH=16 TOPK=16

// ---------- k_wprep: weight transposes + (block 656) cosine-topk bias ----------
__global__ void k_wprep(const float* __restrict__ Wq, const float* __restrict__ Wk,
                        const float* __restrict__ Wv, const float* __restrict__ Wo,
                        const float* __restrict__ W1, const float* __restrict__ W2,
                        const float* __restrict__ conv_w, const float* __restrict__ conv_b,
                        const float* __restrict__ emb,
                        u16* __restrict__ WqT, u16* __restrict__ WkT,
                        u16* __restrict__ WvT, u16* __restrict__ WoT,
                        u16* __restrict__ W1T, u16* __restrict__ W2T,
                        float* __restrict__ cwT, float* __restrict__ cbT,
                        float* __restrict__ bias) {
  __shared__ float sh[8320];   // e[4096] | nrm[64] | cosr[64*65] (bias block only)
  int tid = threadIdx.x;
  if (blockIdx.x == 656) {
    float* e = sh; float* nrm = sh + 4096; float* cosr = sh + 4160;
    for (int idx = tid; idx < 4096; idx += 256) e[idx] = emb[idx];
    __syncthreads();
    if (tid < 64) {
      float s = 0.f;
      for (int j = 0; j < 64; j++) { float v = e[tid * 64 + j]; s += v * v; }
      nrm[tid] = sqrtf(s);
    }
    __syncthreads();
    if (tid < 64) {
      for (int jj = 0; jj < 64; jj++) {
        float d = 0.f;
        for (int kk = 0; kk < 64; kk++) d += e[tid * 64 + kk] * e[jj * 64 + kk];
        cosr[tid * 65 + jj] = d / (nrm[tid] * nrm[jj]);
      }
      unsigned long long sel = 0ull;
      for (int it = 0; it < 16; it++) {
        float best = -1e30f; int bi = 0;
        for (int j = 0; j < 64; j++) {
          if ((sel >> j) & 1ull) continue;
          float cv = cosr[tid * 65 + j];
          if (cv > best) { best = cv; bi = j; }
        }
        sel |= (1ull << bi);
      }
      for (int j = 0; j < 64; j++)
        bias[tid * 64 + j] = ((sel >> j) & 1ull) ? 0.0f : -1e9f;
    }
    return;
  }
  int e = blockIdx.x * 256 + tid;   // 167936 total
  if (e < 98304) {
    int l = e / 49152, r = e % 49152;
    if (r < 16384) {
      int mat = r >> 12, i = r & 4095, n = i >> 6, k = i & 63;
      const float* W = mat == 0 ? Wq : mat == 1 ? Wk : mat == 2 ? Wv : Wo;
      u16* WT = mat == 0 ? WqT : mat == 1 ? WkT : mat == 2 ? WvT : WoT;
      WT[l * 4096 + i] = f2bf(W[l * 4096 + k * 64 + n]);
    } else if (r < 32768) {
      int i = r - 16384, n = i >> 6, k = i & 63;
      W1T[l * 16384 + i] = f2bf(W1[l * 16384 + k * 256 + n]);
    } else {
      int i = r - 32768, n = i >> 8, k = i & 255;
      W2T[l * 16384 + i] = f2bf(W2[l * 16384 + k * 64 + n]);
    }
  } else if (e < 163840) {
    int i = e - 98304;                       // cwT[(n*16+w)*64+d] = conv_w[(d*64+n)*16+w]
    int d = i & 63, w = (i >> 6) & 15, n = i >> 10;
    cwT[i] = conv_w[(d * 64 + n) * 16 + w];
  } else {
    int i = e - 163840;                      // cbT[n*64+d] = conv_b[d*64+n]
    int d = i & 63, n = i >> 6;
    cbT[i] = conv_b[d * 64 + n];
  }
}

// ---------- k_conv: coalesced via transposed weights (cwT[n][w][d], cbT[n][d]) ----------
__global__ void k_conv(const float* __restrict__ x, const float* __restrict__ cwT,
                       const float* __restrict__ cbT, float* __restrict__ h) {
  int bt = blockIdx.x;
  __shared__ float xs[1024];
  int tid = threadIdx.x;
  ((f32x4*)xs)[tid] = ((const f32x4*)(x + ((size_t)bt << 10)))[tid];
  __syncthreads();
  int d = tid & 63, n0 = (tid >> 6) << 4;
  float xv[16];
  #pragma unroll
  for (int w = 0; w < 16; w++) xv[w] = xs[w * 64 + d];
  #pragma unroll
  for (int i = 0; i < 16; i++) {
    int n = n0 + i;
    float acc = cbT[n * 64 + d];
    const float* wp = &cwT[n * 1024 + d];   // lane d -> consecutive addresses
    #pragma unroll
    for (int w = 0; w < 16; w++) acc += xv[w] * wp[w * 64];
    h[((size_t)bt << 12) + n * 64 + d] = acc;
  }
}

// ---------- k_layer2: fused MFMA transformer layer, one (b,t) per block ----------
// r16: exact r14 structure (grid 4096, per-token weight prefetch) -- the r15
// persistent-block variant regressed (lost inter-block phase overlap).
// Phase-3 softmax fully in registers before the barrier. LDS 70656 B.
__global__ __launch_bounds__(256, 2) void k_layer2(
    float* __restrict__ hbuf, const float* __restrict__ emb, const float* __restrict__ bias,
    const u16* __restrict__ WqT, const u16* __restrict__ WkT,
    const u16* __restrict__ WvT, const u16* __restrict__ WoT,
    const u16* __restrict__ W1T, const u16* __restrict__ W2T,
    const float* __restrict__ bq, const float* __restrict__ bk,
    const float* __restrict__ bv, const float* __restrict__ bo,
    const float* __restrict__ ln1g, const float* __restrict__ ln1b,
    const float* __restrict__ ln2g, const float* __restrict__ ln2b,
    const float* __restrict__ b1, const float* __restrict__ b2,
    const float* __restrict__ r1p, const float* __restrict__ r2p,
    u16* __restrict__ aout) {
  __shared__ __align__(16) unsigned char smem[70656];
  float* hres = (float*)smem;                 // [64][68] f32
  __bf16* act = (__bf16*)(smem + 17408);      // [64][72]
  __bf16* qb  = (__bf16*)(smem + 26624);      // [64][136] (per-head 32-wide, hi 16 zero)
  __bf16* kb  = (__bf16*)(smem + 44032);      // [64][136]
  __bf16* vtb = (__bf16*)(smem + 61440);      // [64][72]  V^T [d][node]
  __bf16* ps  = (__bf16*)(smem + 26624);      // [64][264] P, overlays qb+kb
  __bf16* gb  = (__bf16*)(smem + 26624);      // [64][264] FFN hidden, overlays qb+kb

  const int tid = threadIdx.x;
  const int w = tid >> 6, lane = tid & 63;
  const int g = lane >> 4, c = lane & 15;
  const size_t base = (size_t)blockIdx.x << 12;
  const float r1 = *r1p, r2 = *r2p;

  // --- prefetch phase-2/4 weights + biases (latency hides under phase 1) ---
  const int wrow = (w * 16 + c) * 64 + g * 8;
  bf16x8 wq0 = *(const bf16x8*)&WqT[wrow];
  bf16x8 wq1 = *(const bf16x8*)&WqT[wrow + 32];
  bf16x8 wk0 = *(const bf16x8*)&WkT[wrow];
  bf16x8 wk1 = *(const bf16x8*)&WkT[wrow + 32];
  bf16x8 wv0 = *(const bf16x8*)&WvT[wrow];
  bf16x8 wv1 = *(const bf16x8*)&WvT[wrow + 32];
  bf16x8 wo0 = *(const bf16x8*)&WoT[wrow];
  bf16x8 wo1 = *(const bf16x8*)&WoT[wrow + 32];
  f32x4 bq4 = *(const f32x4*)&bq[w * 16 + g * 4];
  f32x4 bk4 = *(const f32x4*)&bk[w * 16 + g * 4];
  f32x4 bo4 = *(const f32x4*)&bo[w * 16 + g * 4];
  f32x4 b24 = *(const f32x4*)&b2[w * 16 + g * 4];
  float bvv = bv[w * 16 + c];

  // phase 1: load h, hin = h+emb -> act(bf16); zero qb/kb (padding lanes)
  #pragma unroll
  for (int i = 0; i < 4; i++) {
    int v = tid + (i << 8);
    f32x4 hv = ((const f32x4*)(hbuf + base))[v];
    f32x4 ev = ((const f32x4*)emb)[v];
    int n = v >> 4, d = (v & 15) << 2;
    *(f32x4*)&hres[n * 68 + d] = hv;
    bf16x4 u;
    u[0] = (__bf16)(hv[0] + ev[0]); u[1] = (__bf16)(hv[1] + ev[1]);
    u[2] = (__bf16)(hv[2] + ev[2]); u[3] = (__bf16)(hv[3] + ev[3]);
    *(bf16x4*)&act[n * 72 + d] = u;
  }
  for (int i = tid; i < 2176; i += 256) {
    f32x4 z; z[0] = 0.f; z[1] = 0.f; z[2] = 0.f; z[3] = 0.f;
    ((f32x4*)(smem + 26624))[i] = z;
  }
  __syncthreads();   // bar1

  bf16x8 af[4][2];
  auto load_af_act = [&]() {
    #pragma unroll
    for (int rt = 0; rt < 4; rt++)
      #pragma unroll
      for (int ks = 0; ks < 2; ks++)
        af[rt][ks] = *(const bf16x8*)&act[(rt * 16 + c) * 72 + ks * 32 + g * 8];
  };

  // phase 2: QKV. q/k operand-swapped (D[d][n]) -> packed stores into qb/kb[n][d];
  // v unswapped -> packed stores into vtb[d][n].
  load_af_act();
  {
    #pragma unroll
    for (int nt = 0; nt < 4; nt++) {
      f32x4 a; a[0]=0.f; a[1]=0.f; a[2]=0.f; a[3]=0.f;
      a = MFMA(wq0, af[nt][0], a);
      a = MFMA(wq1, af[nt][1], a);
      bf16x4 st;
      #pragma unroll
      for (int jj = 0; jj < 4; jj++) st[jj] = (__bf16)(a[jj] + bq4[jj]);
      *(bf16x4*)&qb[(nt * 16 + c) * 136 + w * 32 + g * 4] = st;
    }
    #pragma unroll
    for (int nt = 0; nt < 4; nt++) {
      f32x4 a; a[0]=0.f; a[1]=0.f; a[2]=0.f; a[3]=0.f;
      a = MFMA(wk0, af[nt][0], a);
      a = MFMA(wk1, af[nt][1], a);
      bf16x4 st;
      #pragma unroll
      for (int jj = 0; jj < 4; jj++) st[jj] = (__bf16)(a[jj] + bk4[jj]);
      *(bf16x4*)&kb[(nt * 16 + c) * 136 + w * 32 + g * 4] = st;
    }
    #pragma unroll
    for (int nt = 0; nt < 4; nt++) {
      f32x4 a; a[0]=0.f; a[1]=0.f; a[2]=0.f; a[3]=0.f;
      a = MFMA(af[nt][0], wv0, a);
      a = MFMA(af[nt][1], wv1, a);
      bf16x4 st;
      #pragma unroll
      for (int jj = 0; jj < 4; jj++) st[jj] = (__bf16)(a[jj] + bvv);
      *(bf16x4*)&vtb[(w * 16 + c) * 72 + nt * 16 + g * 4] = st;
    }
  }
  __syncthreads();   // bar2

  // --- prefetch FFN1 weights + biases (latency hides under attention) ---
  bf16x8 w1f[4][2];
  f32x4 b14[4];
  #pragma unroll
  for (int ft = 0; ft < 4; ft++) {
    int ffb = (w << 6) + (ft << 4);
    w1f[ft][0] = *(const bf16x8*)&W1T[(ffb + c) * 64 + g * 8];
    w1f[ft][1] = *(const bf16x8*)&W1T[(ffb + c) * 64 + 32 + g * 8];
    b14[ft] = *(const f32x4*)&b1[ffb + g * 4];
  }

  // phase 3: attention (row-split: wave w owns query rows 16w..16w+15)
  {
    float bias_r[4][4];
    #pragma unroll
    for (int jj = 0; jj < 4; jj++)
      #pragma unroll
      for (int ct = 0; ct < 4; ct++)
        bias_r[jj][ct] = bias[(w * 16 + g * 4 + jj) * 64 + ct * 16 + c];

    // Stage A: all 4 heads' QK^T into registers
    f32x4 sc4[4][4];   // [head][ct]
    #pragma unroll
    for (int h = 0; h < 4; h++) {
      bf16x8 aq = *(const bf16x8*)&qb[(w * 16 + c) * 136 + h * 32 + g * 8];
      #pragma unroll
      for (int ct = 0; ct < 4; ct++) {
        bf16x8 bk8 = *(const bf16x8*)&kb[(ct * 16 + c) * 136 + h * 32 + g * 8];
        f32x4 z0; z0[0]=0.f; z0[1]=0.f; z0[2]=0.f; z0[3]=0.f;
        sc4[h][ct] = MFMA(aq, bk8, z0);
      }
    }

    // Stage B (registers only): softmax consumes sc4 BEFORE the barrier and
    // overwrites it in place with the normalized probabilities.
    #pragma unroll
    for (int h = 0; h < 4; h++) {
      #pragma unroll
      for (int jj = 0; jj < 4; jj++) {
        float s0 = sc4[h][0][jj] * 0.25f + bias_r[jj][0];
        float s1 = sc4[h][1][jj] * 0.25f + bias_r[jj][1];
        float s2 = sc4[h][2][jj] * 0.25f + bias_r[jj][2];
        float s3 = sc4[h][3][jj] * 0.25f + bias_r[jj][3];
        float m = fmaxf(fmaxf(s0, s1), fmaxf(s2, s3));
        m = fmaxf(m, __shfl_xor(m, 1)); m = fmaxf(m, __shfl_xor(m, 2));
        m = fmaxf(m, __shfl_xor(m, 4)); m = fmaxf(m, __shfl_xor(m, 8));
        float e0 = __expf(s0 - m), e1 = __expf(s1 - m), e2 = __expf(s2 - m), e3 = __expf(s3 - m);
        float sum = e0 + e1 + e2 + e3;
        sum += __shfl_xor(sum, 1); sum += __shfl_xor(sum, 2);
        sum += __shfl_xor(sum, 4); sum += __shfl_xor(sum, 8);
        float inv = __builtin_amdgcn_rcpf(sum);
        sc4[h][0][jj] = e0 * inv;
        sc4[h][1][jj] = e1 * inv;
        sc4[h][2][jj] = e2 * inv;
        sc4[h][3][jj] = e3 * inv;
      }
    }

    DS_DRAIN();        // ensure no qb/kb read is in flight across the barrier
    __syncthreads();   // qb/kb region now dead -> becomes ps

    // Stage B'': store P (bf16) into ps
    #pragma unroll
    for (int h = 0; h < 4; h++) {
      #pragma unroll
      for (int jj = 0; jj < 4; jj++) {
        int prow = w * 16 + g * 4 + jj;
        ps[prow * 264 + h * 64 +  0 + c] = (__bf16)sc4[h][0][jj];
        ps[prow * 264 + h * 64 + 16 + c] = (__bf16)sc4[h][1][jj];
        ps[prow * 264 + h * 64 + 32 + c] = (__bf16)sc4[h][2][jj];
        ps[prow * 264 + h * 64 + 48 + c] = (__bf16)sc4[h][3][jj];
      }
    }
    __syncthreads();   // P visible

    // Stage C: PV operand-swapped (D[dh][q]) -> packed bf16x4 act stores
    #pragma unroll
    for (int h = 0; h < 4; h++) {
      f32x4 oacc; oacc[0]=0.f; oacc[1]=0.f; oacc[2]=0.f; oacc[3]=0.f;
      #pragma unroll
      for (int ks = 0; ks < 2; ks++) {
        bf16x8 ap  = *(const bf16x8*)&ps[(w * 16 + c) * 264 + h * 64 + ks * 32 + g * 8];
        bf16x8 bv8 = *(const bf16x8*)&vtb[(h * 16 + c) * 72 + ks * 32 + g * 8];
        oacc = MFMA(bv8, ap, oacc);   // A=V^T[dh][key], B=P^T[key][q]
      }
      bf16x4 st;
      #pragma unroll
      for (int jj = 0; jj < 4; jj++) st[jj] = (__bf16)oacc[jj];
      *(bf16x4*)&act[(w * 16 + c) * 72 + h * 16 + g * 4] = st;
    }
  }
  __syncthreads();   // bar3

  // phase 4: proj + residual (operand-swapped: D[d][n] -> f32x4 RMW on hres)
  load_af_act();
  {
    #pragma unroll
    for (int nt = 0; nt < 4; nt++) {
      f32x4 a; a[0]=0.f; a[1]=0.f; a[2]=0.f; a[3]=0.f;
      a = MFMA(wo0, af[nt][0], a);
      a = MFMA(wo1, af[nt][1], a);
      float* hp = &hres[(nt * 16 + c) * 68 + w * 16 + g * 4];
      f32x4 hv = *(f32x4*)hp;
      #pragma unroll
      for (int jj = 0; jj < 4; jj++) hv[jj] += r1 * (a[jj] + bo4[jj]);
      *(f32x4*)hp = hv;
    }
  }
  __syncthreads();   // bar4

  // phase 5: LN1 -> act (bf16 FFN input) AND hres (fp32 residual)
  {
    int row = w * 16 + (lane >> 2), c0 = (lane & 3) << 4;
    float s = 0.f, s2 = 0.f;
    #pragma unroll
    for (int jv = 0; jv < 4; jv++) {
      f32x4 v = *(const f32x4*)&hres[row * 68 + c0 + jv * 4];
      s += v[0] + v[1] + v[2] + v[3];
      s2 += v[0]*v[0] + v[1]*v[1] + v[2]*v[2] + v[3]*v[3];
    }
    s += __shfl_xor(s, 1);  s += __shfl_xor(s, 2);
    s2 += __shfl_xor(s2, 1); s2 += __shfl_xor(s2, 2);
    float mean = s * 0.015625f, var = s2 * 0.015625f - mean * mean;
    float rstd = rsqrtf(var + 1e-5f);
    #pragma unroll
    for (int jv = 0; jv < 4; jv++) {
      f32x4 v = *(const f32x4*)&hres[row * 68 + c0 + jv * 4];
      f32x4 gg = *(const f32x4*)&ln1g[c0 + jv * 4];
      f32x4 bb = *(const f32x4*)&ln1b[c0 + jv * 4];
      f32x4 o; bf16x4 ob;
      #pragma unroll
      for (int e = 0; e < 4; e++) {
        o[e] = (v[e] - mean) * rstd * gg[e] + bb[e];
        ob[e] = (__bf16)o[e];
      }
      *(f32x4*)&hres[row * 68 + c0 + jv * 4] = o;
      *(bf16x4*)&act[row * 72 + c0 + jv * 4] = ob;
    }
  }
  __syncthreads();   // bar5

  // phase 6: FFN1 operand-swapped (D[ff][n]); weights prefetched (w1f/b14).
  load_af_act();
  // --- prefetch FFN2 weights (latency hides under FFN1 MFMA+gelu) ---
  bf16x8 w2f[8];
  #pragma unroll
  for (int ks = 0; ks < 8; ks++)
    w2f[ks] = *(const bf16x8*)&W2T[(w * 16 + c) * 256 + ks * 32 + g * 8];
  #pragma unroll
  for (int ft = 0; ft < 4; ft++) {
    int ffb = (w << 6) + (ft << 4);
    #pragma unroll
    for (int nt = 0; nt < 4; nt++) {
      f32x4 a; a[0]=0.f; a[1]=0.f; a[2]=0.f; a[3]=0.f;
      a = MFMA(w1f[ft][0], af[nt][0], a);
      a = MFMA(w1f[ft][1], af[nt][1], a);
      bf16x4 st;
      #pragma unroll
      for (int jj = 0; jj < 4; jj++) {
        float xg = a[jj] + b14[ft][jj];
        float e = __expf(1.5957691216057308f * (xg + 0.044715f * xg * xg * xg));
        float r = __builtin_amdgcn_rcpf(1.f + e);
        st[jj] = (__bf16)(xg - xg * r);
      }
      *(bf16x4*)&gb[(nt * 16 + c) * 264 + ffb + g * 4] = st;
    }
  }
  __syncthreads();   // bar6

  // phase 7: FFN2 + residual (operand-swapped: D[d][n] -> f32x4 RMW on hres)
  {
    f32x4 a2[4];
    #pragma unroll
    for (int nt = 0; nt < 4; nt++) { a2[nt][0]=0.f; a2[nt][1]=0.f; a2[nt][2]=0.f; a2[nt][3]=0.f; }
    #pragma unroll
    for (int ks = 0; ks < 8; ks++) {
      #pragma unroll
      for (int nt = 0; nt < 4; nt++) {
        bf16x8 ag = *(const bf16x8*)&gb[(nt * 16 + c) * 264 + ks * 32 + g * 8];
        a2[nt] = MFMA(w2f[ks], ag, a2[nt]);
      }
    }
    #pragma unroll
    for (int nt = 0; nt < 4; nt++) {
      float* hp = &hres[(nt * 16 + c) * 68 + w * 16 + g * 4];
      f32x4 hv = *(f32x4*)hp;
      #pragma unroll
      for (int jj = 0; jj < 4; jj++) hv[jj] += r2 * (a2[nt][jj] + b24[jj]);
      *(f32x4*)hp = hv;
    }
  }
  __syncthreads();   // bar7

  // phase 8: LN2 -> hbuf (fp32) or fused packA -> aout (bf16 GEMM A)
  {
    int row = w * 16 + (lane >> 2), c0 = (lane & 3) << 4;
    float s = 0.f, s2 = 0.f;
    #pragma unroll
    for (int jv = 0; jv < 4; jv++) {
      f32x4 v = *(const f32x4*)&hres[row * 68 + c0 + jv * 4];
      s += v[0] + v[1] + v[2] + v[3];
      s2 += v[0]*v[0] + v[1]*v[1] + v[2]*v[2] + v[3]*v[3];
    }
    s += __shfl_xor(s, 1);  s += __shfl_xor(s, 2);
    s2 += __shfl_xor(s2, 1); s2 += __shfl_xor(s2, 2);
    float mean = s * 0.015625f, var = s2 * 0.015625f - mean * mean;
    float rstd = rsqrtf(var + 1e-5f);
    if (aout) {
      int b = (int)(blockIdx.x >> 8), t = (int)(blockIdx.x & 255);
      __bf16* ao = (__bf16*)aout + (((size_t)(b * 64 + row)) << 14) + (t << 6) + c0;
      #pragma unroll
      for (int jv = 0; jv < 4; jv++) {
        f32x4 v = *(const f32x4*)&hres[row * 68 + c0 + jv * 4];
        f32x4 gg = *(const f32x4*)&ln2g[c0 + jv * 4];
        f32x4 bb = *(const f32x4*)&ln2b[c0 + jv * 4];
        bf16x4 us;
        #pragma unroll
        for (int e = 0; e < 4; e++)
          us[e] = (__bf16)((v[e] - mean) * rstd * gg[e] + bb[e]);
        *(bf16x4*)&ao[jv * 4] = us;
      }
    } else {
      #pragma unroll
      for (int jv = 0; jv < 4; jv++) {
        f32x4 v = *(const f32x4*)&hres[row * 68 + c0 + jv * 4];
        f32x4 gg = *(const f32x4*)&ln2g[c0 + jv * 4];
        f32x4 bb = *(const f32x4*)&ln2b[c0 + jv * 4];
        f32x4 o;
        #pragma unroll
        for (int e = 0; e < 4; e++)
          o[e] = (v[e] - mean) * rstd * gg[e] + bb[e];
        *(f32x4*)&hbuf[base + row * 64 + c0 + jv * 4] = o;
      }
    }
  }
}

// ---------- k_transpose: lin_w [16384][4096] f32 -> wt [4096][16384] bf16 ----------
__global__ __launch_bounds__(256) void k_transpose(const float* __restrict__ w,
                                                   u16* __restrict__ wt) {
  __shared__ u16 tb[128 * 256];   // 64 KB
  const int bn = blockIdx.x & 15;   // 16 n-tiles of 256
  const int bk = blockIdx.x >> 4;   // 128 k-tiles of 128
  const int tid = threadIdx.x;
  #pragma unroll
  for (int i = 0; i < 32; i++) {
    int chunk = i * 256 + tid;
    int row = chunk >> 6, cq = chunk & 63;
    f32x4 v = *(const f32x4*)&w[((size_t)(bk * 128 + row)) * 4096 + bn * 256 + cq * 4];
    ushort4 u;
    u.x = f2bf(v[0]); u.y = f2bf(v[1]); u.z = f2bf(v[2]); u.w = f2bf(v[3]);
    int pc = cq ^ ((row >> 2) & 15);
    *(ushort4*)&tb[row * 256 + pc * 4] = u;
  }
  __syncthreads();
  #pragma unroll
  for (int i = 0; i < 32; i++) {
    int chunk = i * 256 + tid;
    int n = chunk >> 5, kq = chunk & 31;
    int pc = (n >> 2) ^ (kq & 15);
    int nl = n & 3;
    ushort4 u;
    u.x = tb[(kq * 4 + 0) * 256 + pc * 4 + nl];
    u.y = tb[(kq * 4 + 1) * 256 + pc * 4 + nl];
    u.z = tb[(kq * 4 + 2) * 256 + pc * 4 + nl];
    u.w = tb[(kq * 4 + 3) * 256 + pc * 4 + nl];
    *(ushort4*)&wt[((size_t)(bn * 256 + n)) * 16384 + bk * 128 + kq * 4] = u;
  }
}

// ---------- k_gemm3: 256x128 tile, K-split x4, 512 blocks, XOR-swizzled LDS ----------
__global__ __launch_bounds__(256, 2) void k_gemm3(const u16* __restrict__ A,
                                                  const u16* __restrict__ Bt,
                                                  float* __restrict__ P) {
  __shared__ u16 As[256 * 64];   // 32 KB
  __shared__ u16 Bs[128 * 64];   // 16 KB
  const int tid = threadIdx.x;
  const int lane = tid & 63;
  const int wv = tid >> 6;
  const int bid = ((blockIdx.x & 7) << 6) | (blockIdx.x >> 3);
  const int split = bid >> 7;
  const int tile = bid & 127;
  const int bm = tile >> 5, bn = tile & 31;
  const int m0 = bm << 8, n0 = bn << 7;
  f32x4 acc[4][8];
  #pragma unroll
  for (int i = 0; i < 4; i++)
    #pragma unroll
    for (int j = 0; j < 8; j++) { acc[i][j][0]=0.f; acc[i][j][1]=0.f; acc[i][j][2]=0.f; acc[i][j][3]=0.f; }

  const int r15 = lane & 15;
  const int g = lane >> 4;
  const u16* abase = A  + ((size_t)m0 << 14) + (split << 12);
  const u16* bbase = Bt + ((size_t)n0 << 14) + (split << 12);

  for (int kt = 0; kt < 64; kt++) {
    const u16* ab = abase + (kt << 6);
    const u16* bb = bbase + (kt << 6);
    #pragma unroll
    for (int j = 0; j < 8; j++) {
      int cix = (j << 8) + tid;
      int row = cix >> 3;
      int sc  = (cix & 7) ^ (row & 7);
      int off = (row << 14) + (sc << 3);
      __builtin_amdgcn_global_load_lds(AS1(ab + off), AS3(&As[(j << 11) + (wv << 9)]), 16, 0, 0);
    }
    #pragma unroll
    for (int j = 0; j < 4; j++) {
      int cix = (j << 8) + tid;
      int row = cix >> 3;
      int sc  = (cix & 7) ^ (row & 7);
      int off = (row << 14) + (sc << 3);
      __builtin_amdgcn_global_load_lds(AS1(bb + off), AS3(&Bs[(j << 11) + (wv << 9)]), 16, 0, 0);
    }
    __syncthreads();
    #pragma unroll
    for (int ks = 0; ks < 2; ks++) {
      const int pc = ((ks << 2) + g) ^ (r15 & 7);
      bf16x8 af2[4], bfr[8];
      #pragma unroll
      for (int mi = 0; mi < 4; mi++)
        af2[mi] = *(const bf16x8*)&As[((wv << 6) + mi * 16 + r15) * 64 + (pc << 3)];
      #pragma unroll
      for (int ni = 0; ni < 8; ni++)
        bfr[ni] = *(const bf16x8*)&Bs[(ni * 16 + r15) * 64 + (pc << 3)];
      #pragma unroll
      for (int mi = 0; mi < 4; mi++)
        #pragma unroll
        for (int ni = 0; ni < 8; ni++)
          acc[mi][ni] = MFMA(af2[mi], bfr[ni], acc[mi][ni]);
    }
    __syncthreads();
  }

  float* Pp = P + ((size_t)split << 22);
  #pragma unroll
  for (int mi = 0; mi < 4; mi++) {
    #pragma unroll
    for (int ni = 0; ni < 8; ni++) {
      int col = n0 + ni * 16 + r15;
      #pragma unroll
      for (int j = 0; j < 4; j++) {
        int row = m0 + (wv << 6) + mi * 16 + (g << 2) + j;
        Pp[((size_t)row << 12) + col] = acc[mi][ni][j];
      }
    }
  }
}

// ---------- k_reduce: sum 4 K-splits + bias, transpose to out[b,l,n] ----------
__global__ void k_reduce(const float* __restrict__ P, const float* __restrict__ lin_b,
                         float* __restrict__ out) {
  __shared__ float tile[64][65];
  int b = blockIdx.x >> 6, lt = blockIdx.x & 63;
  int tid = threadIdx.x, c = tid & 63, r0 = tid >> 6;
  const float* Pb = P + (((size_t)b * 64) << 12) + (lt << 6);
  #pragma unroll
  for (int i = 0; i < 16; i++) {
    int node = r0 + i * 4;
    size_t off = ((size_t)node << 12) + c;
    float s = Pb[off] + Pb[off + 4194304] + Pb[off + 8388608] + Pb[off + 12582912];
    tile[node][c] = s;
  }
  __syncthreads();
  #pragma unroll
  for (int i = 0; i < 16; i++) {
    int lo = r0 + i * 4;
    out[((size_t)(b * 4096 + lt * 64 + lo)) * 64 + c] = tile[c][lo] + lin_b[lt * 64 + lo];
  }
}

// ---------- launch ----------
extern "C" void kernel_launch(void* const* d_in, const int* in_sizes, int n_in,
                              void* d_out, int out_size, void* d_ws, size_t ws_size,
                              hipStream_t stream) {
  const float* x      = (const float*)d_in[0];
  const float* emb    = (const float*)d_in[1];
  const float* conv_w = (const float*)d_in[2];
  const float* conv_b = (const float*)d_in[3];
  const float* Wq = (const float*)d_in[4],  *bq = (const float*)d_in[5];
  const float* Wk = (const float*)d_in[6],  *bk = (const float*)d_in[7];
  const float* Wv = (const float*)d_in[8],  *bv = (const float*)d_in[9];
  const float* Wo = (const float*)d_in[10], *bo = (const float*)d_in[11];
  const float* ln1g = (const float*)d_in[12], *ln1b = (const float*)d_in[13];
  const float* ln2g = (const float*)d_in[14], *ln2b = (const float*)d_in[15];
  const float* W1 = (const float*)d_in[16], *b1 = (const float*)d_in[17];
  const float* W2 = (const float*)d_in[18], *b2 = (const float*)d_in[19];
  const float* res1 = (const float*)d_in[20], *res2 = (const float*)d_in[21];
  const float* lin_w = (const float*)d_in[22], *lin_b = (const float*)d_in[23];
  float* out = (float*)d_out;

  char* ws = (char*)d_ws;
  float* bias   = (float*)ws;                                        //    16,384 B
  float* hbuf   = (float*)(ws + 16384);                              // 67,108,864 B (layers)
  float* Ppart  = hbuf;                                              // overlay: GEMM partials (after layers)
  u16*   wt     = (u16*)(ws + 16384 + 67108864);                     // 134,217,728 B
  u16*   Abf    = (u16*)(ws + 16384 + 67108864 + 134217728);         // 33,554,432 B
  u16*   WTb    = (u16*)(ws + 16384 + 67108864 + 134217728 + 33554432); // 196,608 B
  u16* WqT = WTb;                 // 8192 elems (2 layers)
  u16* WkT = WTb + 8192;
  u16* WvT = WTb + 16384;
  u16* WoT = WTb + 24576;
  u16* W1T = WTb + 32768;         // 32768 elems
  u16* W2T = WTb + 65536;         // 32768 elems
  // conv transposed weights live in the dead PREFIX of Abf (k_conv runs before
  // the layers; layer-1's fused packA overwrites this region afterwards).
  float* cwT = (float*)Abf;       // 65536 f32 = 262,144 B
  float* cbT = cwT + 65536;       //  4096 f32 =  16,384 B

  k_wprep<<<657, 256, 0, stream>>>(Wq, Wk, Wv, Wo, W1, W2, conv_w, conv_b, emb,
                                   WqT, WkT, WvT, WoT, W1T, W2T, cwT, cbT, bias);
  k_conv<<<4096, 256, 0, stream>>>(x, cwT, cbT, hbuf);
  k_transpose<<<2048, 256, 0, stream>>>(lin_w, wt);
  for (int l = 0; l < 2; l++)
    k_layer2<<<4096, 256, 0, stream>>>(hbuf, emb, bias,
        WqT + l * 4096, WkT + l * 4096, WvT + l * 4096, WoT + l * 4096,
        W1T + l * 16384, W2T + l * 16384,
        bq + l * 64, bk + l * 64, bv + l * 64, bo + l * 64,
        ln1g + l * 64, ln1b + l * 64, ln2g + l * 64, ln2b + l * 64,
        b1 + l * 256, b2 + l * 64, res1 + l, res2 + l,
        (l == 1) ? Abf : (u16*)nullptr);
  k_gemm3<<<512, 256, 0, stream>>>(Abf, wt, Ppart);
  k_reduce<<<1024, 256, 0, stream>>>(Ppart, lin_b, out);
}

// Round 17
// 635.967 us; speedup vs baseline: 1.1410x; 1.0140x over previous
//
#include <hip/hip_runtime.h>
#include <hip/hip_bf16.h>
#include <stdint.h>

// ---------- helpers ----------
#define AS1(p) ((const __attribute__((address_space(1))) void*)(p))
#define AS3(p) ((__attribute__((address_space(3))) void*)(p))

typedef __bf16 bf16x8 __attribute__((ext_vector_type(8)));
typedef __bf16 bf16x4 __attribute__((ext_vector_type(4)));
typedef float f32x4 __attribute__((ext_vector_type(4)));
typedef unsigned short u16;

#define MFMA(a, b, cc) __builtin_amdgcn_mfma_f32_16x16x32_bf16(a, b, cc, 0, 0, 0)
// Drain outstanding DS ops (reads included) BEFORE a barrier (r8 lesson).
#define DS_DRAIN() asm volatile("s_waitcnt lgkmcnt(0)" ::: "memory")

__device__ __forceinline__ u16 f2bf(float f) {
  unsigned u = __builtin_bit_cast(unsigned, f);
  u = (u + 0x7FFFu + ((u >> 16) & 1u)) >> 16;   // RNE
  return (u16)u;
}

// ---------- constants ----------
// B=16 L=4096 N=64 D=64 H=4 WAVE=16 T=256 DFF=256 DH=16 TOPK=16

// ---------- k_wprep: weight transposes + (block 656) cosine-topk bias ----------
__global__ void k_wprep(const float* __restrict__ Wq, const float* __restrict__ Wk,
                        const float* __restrict__ Wv, const float* __restrict__ Wo,
                        const float* __restrict__ W1, const float* __restrict__ W2,
                        const float* __restrict__ conv_w, const float* __restrict__ conv_b,
                        const float* __restrict__ emb,
                        u16* __restrict__ WqT, u16* __restrict__ WkT,
                        u16* __restrict__ WvT, u16* __restrict__ WoT,
                        u16* __restrict__ W1T, u16* __restrict__ W2T,
                        float* __restrict__ cwT, float* __restrict__ cbT,
                        float* __restrict__ bias) {
  __shared__ float sh[8320];   // e[4096] | nrm[64] | cosr[64*65] (bias block only)
  int tid = threadIdx.x;
  if (blockIdx.x == 656) {
    float* e = sh; float* nrm = sh + 4096; float* cosr = sh + 4160;
    for (int idx = tid; idx < 4096; idx += 256) e[idx] = emb[idx];
    __syncthreads();
    if (tid < 64) {
      float s = 0.f;
      for (int j = 0; j < 64; j++) { float v = e[tid * 64 + j]; s += v * v; }
      nrm[tid] = sqrtf(s);
    }
    __syncthreads();
    if (tid < 64) {
      for (int jj = 0; jj < 64; jj++) {
        float d = 0.f;
        for (int kk = 0; kk < 64; kk++) d += e[tid * 64 + kk] * e[jj * 64 + kk];
        cosr[tid * 65 + jj] = d / (nrm[tid] * nrm[jj]);
      }
      unsigned long long sel = 0ull;
      for (int it = 0; it < 16; it++) {
        float best = -1e30f; int bi = 0;
        for (int j = 0; j < 64; j++) {
          if ((sel >> j) & 1ull) continue;
          float cv = cosr[tid * 65 + j];
          if (cv > best) { best = cv; bi = j; }
        }
        sel |= (1ull << bi);
      }
      for (int j = 0; j < 64; j++)
        bias[tid * 64 + j] = ((sel >> j) & 1ull) ? 0.0f : -1e9f;
    }
    return;
  }
  int e = blockIdx.x * 256 + tid;   // 167936 total
  if (e < 98304) {
    int l = e / 49152, r = e % 49152;
    if (r < 16384) {
      int mat = r >> 12, i = r & 4095, n = i >> 6, k = i & 63;
      const float* W = mat == 0 ? Wq : mat == 1 ? Wk : mat == 2 ? Wv : Wo;
      u16* WT = mat == 0 ? WqT : mat == 1 ? WkT : mat == 2 ? WvT : WoT;
      WT[l * 4096 + i] = f2bf(W[l * 4096 + k * 64 + n]);
    } else if (r < 32768) {
      int i = r - 16384, n = i >> 6, k = i & 63;
      W1T[l * 16384 + i] = f2bf(W1[l * 16384 + k * 256 + n]);
    } else {
      int i = r - 32768, n = i >> 8, k = i & 255;
      W2T[l * 16384 + i] = f2bf(W2[l * 16384 + k * 64 + n]);
    }
  } else if (e < 163840) {
    int i = e - 98304;                       // cwT[(n*16+w)*64+d] = conv_w[(d*64+n)*16+w]
    int d = i & 63, w = (i >> 6) & 15, n = i >> 10;
    cwT[i] = conv_w[(d * 64 + n) * 16 + w];
  } else {
    int i = e - 163840;                      // cbT[n*64+d] = conv_b[d*64+n]
    int d = i & 63, n = i >> 6;
    cbT[i] = conv_b[d * 64 + n];
  }
}

// ---------- k_conv: 8 tokens x 16-n group per block; weights register-resident ----------
// r17: old version streamed the full 256 KB cwT per block (4096 blocks -> ~1 GB
// L2 traffic). Now each thread keeps its 4n x 16w slice in VGPRs across 8 tokens
// (cwT traffic 1 GB -> 32 MB). Same FMA order per output -> bit-identical h.
__global__ __launch_bounds__(256) void k_conv(const float* __restrict__ x,
                                              const float* __restrict__ cwT,
                                              const float* __restrict__ cbT,
                                              float* __restrict__ h) {
  __shared__ float xs[8192];          // 8 tokens x 1024
  const int tc = blockIdx.x >> 2;     // 512 token-chunks of 8
  const int ng = blockIdx.x & 3;      // 4 n-groups of 16
  const int tid = threadIdx.x;
  const int d = tid & 63, nsub = tid >> 6;
  #pragma unroll
  for (int i = 0; i < 8; i++)
    ((f32x4*)xs)[i * 256 + tid] = ((const f32x4*)(x + ((size_t)tc << 13)))[i * 256 + tid];
  float wv[4][16];
  float cb[4];
  #pragma unroll
  for (int i = 0; i < 4; i++) {
    int n = (ng << 4) + (nsub << 2) + i;
    cb[i] = cbT[n * 64 + d];
    #pragma unroll
    for (int w = 0; w < 16; w++) wv[i][w] = cwT[n * 1024 + w * 64 + d];
  }
  __syncthreads();
  for (int t = 0; t < 8; t++) {
    float xv[16];
    #pragma unroll
    for (int w = 0; w < 16; w++) xv[w] = xs[t * 1024 + w * 64 + d];
    #pragma unroll
    for (int i = 0; i < 4; i++) {
      int n = (ng << 4) + (nsub << 2) + i;
      float acc = cb[i];
      #pragma unroll
      for (int w = 0; w < 16; w++) acc += xv[w] * wv[i][w];
      h[(((size_t)(tc * 8 + t)) << 12) + n * 64 + d] = acc;
    }
  }
}

// ---------- k_layer2: fused MFMA transformer layer, one (b,t) per block ----------
// (byte-identical to r16: grid 4096, per-token prefetch, in-register softmax)
__global__ __launch_bounds__(256, 2) void k_layer2(
    float* __restrict__ hbuf, const float* __restrict__ emb, const float* __restrict__ bias,
    const u16* __restrict__ WqT, const u16* __restrict__ WkT,
    const u16* __restrict__ WvT, const u16* __restrict__ WoT,
    const u16* __restrict__ W1T, const u16* __restrict__ W2T,
    const float* __restrict__ bq, const float* __restrict__ bk,
    const float* __restrict__ bv, const float* __restrict__ bo,
    const float* __restrict__ ln1g, const float* __restrict__ ln1b,
    const float* __restrict__ ln2g, const float* __restrict__ ln2b,
    const float* __restrict__ b1, const float* __restrict__ b2,
    const float* __restrict__ r1p, const float* __restrict__ r2p,
    u16* __restrict__ aout) {
  __shared__ __align__(16) unsigned char smem[70656];
  float* hres = (float*)smem;                 // [64][68] f32
  __bf16* act = (__bf16*)(smem + 17408);      // [64][72]
  __bf16* qb  = (__bf16*)(smem + 26624);      // [64][136] (per-head 32-wide, hi 16 zero)
  __bf16* kb  = (__bf16*)(smem + 44032);      // [64][136]
  __bf16* vtb = (__bf16*)(smem + 61440);      // [64][72]  V^T [d][node]
  __bf16* ps  = (__bf16*)(smem + 26624);      // [64][264] P, overlays qb+kb
  __bf16* gb  = (__bf16*)(smem + 26624);      // [64][264] FFN hidden, overlays qb+kb

  const int tid = threadIdx.x;
  const int w = tid >> 6, lane = tid & 63;
  const int g = lane >> 4, c = lane & 15;
  const size_t base = (size_t)blockIdx.x << 12;
  const float r1 = *r1p, r2 = *r2p;

  // --- prefetch phase-2/4 weights + biases (latency hides under phase 1) ---
  const int wrow = (w * 16 + c) * 64 + g * 8;
  bf16x8 wq0 = *(const bf16x8*)&WqT[wrow];
  bf16x8 wq1 = *(const bf16x8*)&WqT[wrow + 32];
  bf16x8 wk0 = *(const bf16x8*)&WkT[wrow];
  bf16x8 wk1 = *(const bf16x8*)&WkT[wrow + 32];
  bf16x8 wv0 = *(const bf16x8*)&WvT[wrow];
  bf16x8 wv1 = *(const bf16x8*)&WvT[wrow + 32];
  bf16x8 wo0 = *(const bf16x8*)&WoT[wrow];
  bf16x8 wo1 = *(const bf16x8*)&WoT[wrow + 32];
  f32x4 bq4 = *(const f32x4*)&bq[w * 16 + g * 4];
  f32x4 bk4 = *(const f32x4*)&bk[w * 16 + g * 4];
  f32x4 bo4 = *(const f32x4*)&bo[w * 16 + g * 4];
  f32x4 b24 = *(const f32x4*)&b2[w * 16 + g * 4];
  float bvv = bv[w * 16 + c];

  // phase 1: load h, hin = h+emb -> act(bf16); zero qb/kb (padding lanes)
  #pragma unroll
  for (int i = 0; i < 4; i++) {
    int v = tid + (i << 8);
    f32x4 hv = ((const f32x4*)(hbuf + base))[v];
    f32x4 ev = ((const f32x4*)emb)[v];
    int n = v >> 4, d = (v & 15) << 2;
    *(f32x4*)&hres[n * 68 + d] = hv;
    bf16x4 u;
    u[0] = (__bf16)(hv[0] + ev[0]); u[1] = (__bf16)(hv[1] + ev[1]);
    u[2] = (__bf16)(hv[2] + ev[2]); u[3] = (__bf16)(hv[3] + ev[3]);
    *(bf16x4*)&act[n * 72 + d] = u;
  }
  for (int i = tid; i < 2176; i += 256) {
    f32x4 z; z[0] = 0.f; z[1] = 0.f; z[2] = 0.f; z[3] = 0.f;
    ((f32x4*)(smem + 26624))[i] = z;
  }
  __syncthreads();   // bar1

  bf16x8 af[4][2];
  auto load_af_act = [&]() {
    #pragma unroll
    for (int rt = 0; rt < 4; rt++)
      #pragma unroll
      for (int ks = 0; ks < 2; ks++)
        af[rt][ks] = *(const bf16x8*)&act[(rt * 16 + c) * 72 + ks * 32 + g * 8];
  };

  // phase 2: QKV. q/k operand-swapped (D[d][n]) -> packed stores into qb/kb[n][d];
  // v unswapped -> packed stores into vtb[d][n].
  load_af_act();
  {
    #pragma unroll
    for (int nt = 0; nt < 4; nt++) {
      f32x4 a; a[0]=0.f; a[1]=0.f; a[2]=0.f; a[3]=0.f;
      a = MFMA(wq0, af[nt][0], a);
      a = MFMA(wq1, af[nt][1], a);
      bf16x4 st;
      #pragma unroll
      for (int jj = 0; jj < 4; jj++) st[jj] = (__bf16)(a[jj] + bq4[jj]);
      *(bf16x4*)&qb[(nt * 16 + c) * 136 + w * 32 + g * 4] = st;
    }
    #pragma unroll
    for (int nt = 0; nt < 4; nt++) {
      f32x4 a; a[0]=0.f; a[1]=0.f; a[2]=0.f; a[3]=0.f;
      a = MFMA(wk0, af[nt][0], a);
      a = MFMA(wk1, af[nt][1], a);
      bf16x4 st;
      #pragma unroll
      for (int jj = 0; jj < 4; jj++) st[jj] = (__bf16)(a[jj] + bk4[jj]);
      *(bf16x4*)&kb[(nt * 16 + c) * 136 + w * 32 + g * 4] = st;
    }
    #pragma unroll
    for (int nt = 0; nt < 4; nt++) {
      f32x4 a; a[0]=0.f; a[1]=0.f; a[2]=0.f; a[3]=0.f;
      a = MFMA(af[nt][0], wv0, a);
      a = MFMA(af[nt][1], wv1, a);
      bf16x4 st;
      #pragma unroll
      for (int jj = 0; jj < 4; jj++) st[jj] = (__bf16)(a[jj] + bvv);
      *(bf16x4*)&vtb[(w * 16 + c) * 72 + nt * 16 + g * 4] = st;
    }
  }
  __syncthreads();   // bar2

  // --- prefetch FFN1 weights + biases (latency hides under attention) ---
  bf16x8 w1f[4][2];
  f32x4 b14[4];
  #pragma unroll
  for (int ft = 0; ft < 4; ft++) {
    int ffb = (w << 6) + (ft << 4);
    w1f[ft][0] = *(const bf16x8*)&W1T[(ffb + c) * 64 + g * 8];
    w1f[ft][1] = *(const bf16x8*)&W1T[(ffb + c) * 64 + 32 + g * 8];
    b14[ft] = *(const f32x4*)&b1[ffb + g * 4];
  }

  // phase 3: attention (row-split: wave w owns query rows 16w..16w+15)
  {
    float bias_r[4][4];
    #pragma unroll
    for (int jj = 0; jj < 4; jj++)
      #pragma unroll
      for (int ct = 0; ct < 4; ct++)
        bias_r[jj][ct] = bias[(w * 16 + g * 4 + jj) * 64 + ct * 16 + c];

    // Stage A: all 4 heads' QK^T into registers
    f32x4 sc4[4][4];   // [head][ct]
    #pragma unroll
    for (int h = 0; h < 4; h++) {
      bf16x8 aq = *(const bf16x8*)&qb[(w * 16 + c) * 136 + h * 32 + g * 8];
      #pragma unroll
      for (int ct = 0; ct < 4; ct++) {
        bf16x8 bk8 = *(const bf16x8*)&kb[(ct * 16 + c) * 136 + h * 32 + g * 8];
        f32x4 z0; z0[0]=0.f; z0[1]=0.f; z0[2]=0.f; z0[3]=0.f;
        sc4[h][ct] = MFMA(aq, bk8, z0);
      }
    }

    // Stage B (registers only): softmax consumes sc4 BEFORE the barrier and
    // overwrites it in place with the normalized probabilities.
    #pragma unroll
    for (int h = 0; h < 4; h++) {
      #pragma unroll
      for (int jj = 0; jj < 4; jj++) {
        float s0 = sc4[h][0][jj] * 0.25f + bias_r[jj][0];
        float s1 = sc4[h][1][jj] * 0.25f + bias_r[jj][1];
        float s2 = sc4[h][2][jj] * 0.25f + bias_r[jj][2];
        float s3 = sc4[h][3][jj] * 0.25f + bias_r[jj][3];
        float m = fmaxf(fmaxf(s0, s1), fmaxf(s2, s3));
        m = fmaxf(m, __shfl_xor(m, 1)); m = fmaxf(m, __shfl_xor(m, 2));
        m = fmaxf(m, __shfl_xor(m, 4)); m = fmaxf(m, __shfl_xor(m, 8));
        float e0 = __expf(s0 - m), e1 = __expf(s1 - m), e2 = __expf(s2 - m), e3 = __expf(s3 - m);
        float sum = e0 + e1 + e2 + e3;
        sum += __shfl_xor(sum, 1); sum += __shfl_xor(sum, 2);
        sum += __shfl_xor(sum, 4); sum += __shfl_xor(sum, 8);
        float inv = __builtin_amdgcn_rcpf(sum);
        sc4[h][0][jj] = e0 * inv;
        sc4[h][1][jj] = e1 * inv;
        sc4[h][2][jj] = e2 * inv;
        sc4[h][3][jj] = e3 * inv;
      }
    }

    DS_DRAIN();        // ensure no qb/kb read is in flight across the barrier
    __syncthreads();   // qb/kb region now dead -> becomes ps

    // Stage B'': store P (bf16) into ps
    #pragma unroll
    for (int h = 0; h < 4; h++) {
      #pragma unroll
      for (int jj = 0; jj < 4; jj++) {
        int prow = w * 16 + g * 4 + jj;
        ps[prow * 264 + h * 64 +  0 + c] = (__bf16)sc4[h][0][jj];
        ps[prow * 264 + h * 64 + 16 + c] = (__bf16)sc4[h][1][jj];
        ps[prow * 264 + h * 64 + 32 + c] = (__bf16)sc4[h][2][jj];
        ps[prow * 264 + h * 64 + 48 + c] = (__bf16)sc4[h][3][jj];
      }
    }
    __syncthreads();   // P visible

    // Stage C: PV operand-swapped (D[dh][q]) -> packed bf16x4 act stores
    #pragma unroll
    for (int h = 0; h < 4; h++) {
      f32x4 oacc; oacc[0]=0.f; oacc[1]=0.f; oacc[2]=0.f; oacc[3]=0.f;
      #pragma unroll
      for (int ks = 0; ks < 2; ks++) {
        bf16x8 ap  = *(const bf16x8*)&ps[(w * 16 + c) * 264 + h * 64 + ks * 32 + g * 8];
        bf16x8 bv8 = *(const bf16x8*)&vtb[(h * 16 + c) * 72 + ks * 32 + g * 8];
        oacc = MFMA(bv8, ap, oacc);   // A=V^T[dh][key], B=P^T[key][q]
      }
      bf16x4 st;
      #pragma unroll
      for (int jj = 0; jj < 4; jj++) st[jj] = (__bf16)oacc[jj];
      *(bf16x4*)&act[(w * 16 + c) * 72 + h * 16 + g * 4] = st;
    }
  }
  __syncthreads();   // bar3

  // phase 4: proj + residual (operand-swapped: D[d][n] -> f32x4 RMW on hres)
  load_af_act();
  {
    #pragma unroll
    for (int nt = 0; nt < 4; nt++) {
      f32x4 a; a[0]=0.f; a[1]=0.f; a[2]=0.f; a[3]=0.f;
      a = MFMA(wo0, af[nt][0], a);
      a = MFMA(wo1, af[nt][1], a);
      float* hp = &hres[(nt * 16 + c) * 68 + w * 16 + g * 4];
      f32x4 hv = *(f32x4*)hp;
      #pragma unroll
      for (int jj = 0; jj < 4; jj++) hv[jj] += r1 * (a[jj] + bo4[jj]);
      *(f32x4*)hp = hv;
    }
  }
  __syncthreads();   // bar4

  // phase 5: LN1 -> act (bf16 FFN input) AND hres (fp32 residual)
  {
    int row = w * 16 + (lane >> 2), c0 = (lane & 3) << 4;
    float s = 0.f, s2 = 0.f;
    #pragma unroll
    for (int jv = 0; jv < 4; jv++) {
      f32x4 v = *(const f32x4*)&hres[row * 68 + c0 + jv * 4];
      s += v[0] + v[1] + v[2] + v[3];
      s2 += v[0]*v[0] + v[1]*v[1] + v[2]*v[2] + v[3]*v[3];
    }
    s += __shfl_xor(s, 1);  s += __shfl_xor(s, 2);
    s2 += __shfl_xor(s2, 1); s2 += __shfl_xor(s2, 2);
    float mean = s * 0.015625f, var = s2 * 0.015625f - mean * mean;
    float rstd = rsqrtf(var + 1e-5f);
    #pragma unroll
    for (int jv = 0; jv < 4; jv++) {
      f32x4 v = *(const f32x4*)&hres[row * 68 + c0 + jv * 4];
      f32x4 gg = *(const f32x4*)&ln1g[c0 + jv * 4];
      f32x4 bb = *(const f32x4*)&ln1b[c0 + jv * 4];
      f32x4 o; bf16x4 ob;
      #pragma unroll
      for (int e = 0; e < 4; e++) {
        o[e] = (v[e] - mean) * rstd * gg[e] + bb[e];
        ob[e] = (__bf16)o[e];
      }
      *(f32x4*)&hres[row * 68 + c0 + jv * 4] = o;
      *(bf16x4*)&act[row * 72 + c0 + jv * 4] = ob;
    }
  }
  __syncthreads();   // bar5

  // phase 6: FFN1 operand-swapped (D[ff][n]); weights prefetched (w1f/b14).
  load_af_act();
  // --- prefetch FFN2 weights (latency hides under FFN1 MFMA+gelu) ---
  bf16x8 w2f[8];
  #pragma unroll
  for (int ks = 0; ks < 8; ks++)
    w2f[ks] = *(const bf16x8*)&W2T[(w * 16 + c) * 256 + ks * 32 + g * 8];
  #pragma unroll
  for (int ft = 0; ft < 4; ft++) {
    int ffb = (w << 6) + (ft << 4);
    #pragma unroll
    for (int nt = 0; nt < 4; nt++) {
      f32x4 a; a[0]=0.f; a[1]=0.f; a[2]=0.f; a[3]=0.f;
      a = MFMA(w1f[ft][0], af[nt][0], a);
      a = MFMA(w1f[ft][1], af[nt][1], a);
      bf16x4 st;
      #pragma unroll
      for (int jj = 0; jj < 4; jj++) {
        float xg = a[jj] + b14[ft][jj];
        float e = __expf(1.5957691216057308f * (xg + 0.044715f * xg * xg * xg));
        float r = __builtin_amdgcn_rcpf(1.f + e);
        st[jj] = (__bf16)(xg - xg * r);
      }
      *(bf16x4*)&gb[(nt * 16 + c) * 264 + ffb + g * 4] = st;
    }
  }
  __syncthreads();   // bar6

  // phase 7: FFN2 + residual (operand-swapped: D[d][n] -> f32x4 RMW on hres)
  {
    f32x4 a2[4];
    #pragma unroll
    for (int nt = 0; nt < 4; nt++) { a2[nt][0]=0.f; a2[nt][1]=0.f; a2[nt][2]=0.f; a2[nt][3]=0.f; }
    #pragma unroll
    for (int ks = 0; ks < 8; ks++) {
      #pragma unroll
      for (int nt = 0; nt < 4; nt++) {
        bf16x8 ag = *(const bf16x8*)&gb[(nt * 16 + c) * 264 + ks * 32 + g * 8];
        a2[nt] = MFMA(w2f[ks], ag, a2[nt]);
      }
    }
    #pragma unroll
    for (int nt = 0; nt < 4; nt++) {
      float* hp = &hres[(nt * 16 + c) * 68 + w * 16 + g * 4];
      f32x4 hv = *(f32x4*)hp;
      #pragma unroll
      for (int jj = 0; jj < 4; jj++) hv[jj] += r2 * (a2[nt][jj] + b24[jj]);
      *(f32x4*)hp = hv;
    }
  }
  __syncthreads();   // bar7

  // phase 8: LN2 -> hbuf (fp32) or fused packA -> aout (bf16 GEMM A)
  {
    int row = w * 16 + (lane >> 2), c0 = (lane & 3) << 4;
    float s = 0.f, s2 = 0.f;
    #pragma unroll
    for (int jv = 0; jv < 4; jv++) {
      f32x4 v = *(const f32x4*)&hres[row * 68 + c0 + jv * 4];
      s += v[0] + v[1] + v[2] + v[3];
      s2 += v[0]*v[0] + v[1]*v[1] + v[2]*v[2] + v[3]*v[3];
    }
    s += __shfl_xor(s, 1);  s += __shfl_xor(s, 2);
    s2 += __shfl_xor(s2, 1); s2 += __shfl_xor(s2, 2);
    float mean = s * 0.015625f, var = s2 * 0.015625f - mean * mean;
    float rstd = rsqrtf(var + 1e-5f);
    if (aout) {
      int b = (int)(blockIdx.x >> 8), t = (int)(blockIdx.x & 255);
      __bf16* ao = (__bf16*)aout + (((size_t)(b * 64 + row)) << 14) + (t << 6) + c0;
      #pragma unroll
      for (int jv = 0; jv < 4; jv++) {
        f32x4 v = *(const f32x4*)&hres[row * 68 + c0 + jv * 4];
        f32x4 gg = *(const f32x4*)&ln2g[c0 + jv * 4];
        f32x4 bb = *(const f32x4*)&ln2b[c0 + jv * 4];
        bf16x4 us;
        #pragma unroll
        for (int e = 0; e < 4; e++)
          us[e] = (__bf16)((v[e] - mean) * rstd * gg[e] + bb[e]);
        *(bf16x4*)&ao[jv * 4] = us;
      }
    } else {
      #pragma unroll
      for (int jv = 0; jv < 4; jv++) {
        f32x4 v = *(const f32x4*)&hres[row * 68 + c0 + jv * 4];
        f32x4 gg = *(const f32x4*)&ln2g[c0 + jv * 4];
        f32x4 bb = *(const f32x4*)&ln2b[c0 + jv * 4];
        f32x4 o;
        #pragma unroll
        for (int e = 0; e < 4; e++)
          o[e] = (v[e] - mean) * rstd * gg[e] + bb[e];
        *(f32x4*)&hbuf[base + row * 64 + c0 + jv * 4] = o;
      }
    }
  }
}

// ---------- k_transpose: lin_w [16384][4096] f32 -> wt [4096][16384] bf16 ----------
__global__ __launch_bounds__(256) void k_transpose(const float* __restrict__ w,
                                                   u16* __restrict__ wt) {
  __shared__ u16 tb[128 * 256];   // 64 KB
  const int bn = blockIdx.x & 15;   // 16 n-tiles of 256
  const int bk = blockIdx.x >> 4;   // 128 k-tiles of 128
  const int tid = threadIdx.x;
  #pragma unroll
  for (int i = 0; i < 32; i++) {
    int chunk = i * 256 + tid;
    int row = chunk >> 6, cq = chunk & 63;
    f32x4 v = *(const f32x4*)&w[((size_t)(bk * 128 + row)) * 4096 + bn * 256 + cq * 4];
    ushort4 u;
    u.x = f2bf(v[0]); u.y = f2bf(v[1]); u.z = f2bf(v[2]); u.w = f2bf(v[3]);
    int pc = cq ^ ((row >> 2) & 15);
    *(ushort4*)&tb[row * 256 + pc * 4] = u;
  }
  __syncthreads();
  #pragma unroll
  for (int i = 0; i < 32; i++) {
    int chunk = i * 256 + tid;
    int n = chunk >> 5, kq = chunk & 31;
    int pc = (n >> 2) ^ (kq & 15);
    int nl = n & 3;
    ushort4 u;
    u.x = tb[(kq * 4 + 0) * 256 + pc * 4 + nl];
    u.y = tb[(kq * 4 + 1) * 256 + pc * 4 + nl];
    u.z = tb[(kq * 4 + 2) * 256 + pc * 4 + nl];
    u.w = tb[(kq * 4 + 3) * 256 + pc * 4 + nl];
    *(ushort4*)&wt[((size_t)(bn * 256 + n)) * 16384 + bk * 128 + kq * 4] = u;
  }
}

// ---------- k_gemm3: 256x128 tile, K-split x4, 512 blocks, XOR-swizzled LDS ----------
__global__ __launch_bounds__(256, 2) void k_gemm3(const u16* __restrict__ A,
                                                  const u16* __restrict__ Bt,
                                                  float* __restrict__ P) {
  __shared__ u16 As[256 * 64];   // 32 KB
  __shared__ u16 Bs[128 * 64];   // 16 KB
  const int tid = threadIdx.x;
  const int lane = tid & 63;
  const int wv = tid >> 6;
  const int bid = ((blockIdx.x & 7) << 6) | (blockIdx.x >> 3);
  const int split = bid >> 7;
  const int tile = bid & 127;
  const int bm = tile >> 5, bn = tile & 31;
  const int m0 = bm << 8, n0 = bn << 7;
  f32x4 acc[4][8];
  #pragma unroll
  for (int i = 0; i < 4; i++)
    #pragma unroll
    for (int j = 0; j < 8; j++) { acc[i][j][0]=0.f; acc[i][j][1]=0.f; acc[i][j][2]=0.f; acc[i][j][3]=0.f; }

  const int r15 = lane & 15;
  const int g = lane >> 4;
  const u16* abase = A  + ((size_t)m0 << 14) + (split << 12);
  const u16* bbase = Bt + ((size_t)n0 << 14) + (split << 12);

  for (int kt = 0; kt < 64; kt++) {
    const u16* ab = abase + (kt << 6);
    const u16* bb = bbase + (kt << 6);
    #pragma unroll
    for (int j = 0; j < 8; j++) {
      int cix = (j << 8) + tid;
      int row = cix >> 3;
      int sc  = (cix & 7) ^ (row & 7);
      int off = (row << 14) + (sc << 3);
      __builtin_amdgcn_global_load_lds(AS1(ab + off), AS3(&As[(j << 11) + (wv << 9)]), 16, 0, 0);
    }
    #pragma unroll
    for (int j = 0; j < 4; j++) {
      int cix = (j << 8) + tid;
      int row = cix >> 3;
      int sc  = (cix & 7) ^ (row & 7);
      int off = (row << 14) + (sc << 3);
      __builtin_amdgcn_global_load_lds(AS1(bb + off), AS3(&Bs[(j << 11) + (wv << 9)]), 16, 0, 0);
    }
    __syncthreads();
    #pragma unroll
    for (int ks = 0; ks < 2; ks++) {
      const int pc = ((ks << 2) + g) ^ (r15 & 7);
      bf16x8 af2[4], bfr[8];
      #pragma unroll
      for (int mi = 0; mi < 4; mi++)
        af2[mi] = *(const bf16x8*)&As[((wv << 6) + mi * 16 + r15) * 64 + (pc << 3)];
      #pragma unroll
      for (int ni = 0; ni < 8; ni++)
        bfr[ni] = *(const bf16x8*)&Bs[(ni * 16 + r15) * 64 + (pc << 3)];
      #pragma unroll
      for (int mi = 0; mi < 4; mi++)
        #pragma unroll
        for (int ni = 0; ni < 8; ni++)
          acc[mi][ni] = MFMA(af2[mi], bfr[ni], acc[mi][ni]);
    }
    __syncthreads();
  }

  float* Pp = P + ((size_t)split << 22);
  #pragma unroll
  for (int mi = 0; mi < 4; mi++) {
    #pragma unroll
    for (int ni = 0; ni < 8; ni++) {
      int col = n0 + ni * 16 + r15;
      #pragma unroll
      for (int j = 0; j < 4; j++) {
        int row = m0 + (wv << 6) + mi * 16 + (g << 2) + j;
        Pp[((size_t)row << 12) + col] = acc[mi][ni][j];
      }
    }
  }
}

// ---------- k_reduce: sum 4 K-splits + bias -> out[b,l,n]; retiled (r17) ----------
// Block = (b, 256-wide l-chunk): f32x4 reads of 1 KB contiguous P row segments,
// accumulate splits in LDS (order P0+P1+P2+P3 preserved -> bit-identical),
// f32x4 writes of contiguous out rows. Grid 256.
__global__ __launch_bounds__(256) void k_reduce(const float* __restrict__ P,
                                                const float* __restrict__ lin_b,
                                                float* __restrict__ out) {
  __shared__ float acc[64 * 256];   // 64 KB
  const int b = blockIdx.x >> 4;    // 16 batches
  const int lc = blockIdx.x & 15;   // 16 l-chunks of 256
  const int tid = threadIdx.x;
  const int lq = tid & 63;          // l' quad (x4)
  const int nr = tid >> 6;          // n-row group
  const float* Pb = P + (((size_t)(b * 64)) << 12) + (lc << 8);
  #pragma unroll
  for (int i = 0; i < 16; i++) {
    int n = (nr << 4) + i;
    f32x4 v = *(const f32x4*)&Pb[((size_t)n << 12) + (lq << 2)];
    *(f32x4*)&acc[n * 256 + (lq << 2)] = v;
  }
  #pragma unroll
  for (int s = 1; s < 4; s++) {
    const float* Ps = Pb + ((size_t)s << 22);
    #pragma unroll
    for (int i = 0; i < 16; i++) {
      int n = (nr << 4) + i;
      f32x4 v = *(const f32x4*)&Ps[((size_t)n << 12) + (lq << 2)];
      f32x4 a = *(f32x4*)&acc[n * 256 + (lq << 2)];
      a[0] += v[0]; a[1] += v[1]; a[2] += v[2]; a[3] += v[3];
      *(f32x4*)&acc[n * 256 + (lq << 2)] = a;
    }
  }
  __syncthreads();
  // write: thread owns l' = tid; 64 n contiguous per out row
  float lb = lin_b[(lc << 8) + tid];
  float* op = out + (((size_t)(b * 4096 + (lc << 8) + tid)) << 6);
  #pragma unroll
  for (int i = 0; i < 16; i++) {
    f32x4 o;
    #pragma unroll
    for (int j = 0; j < 4; j++) o[j] = acc[(i * 4 + j) * 256 + tid] + lb;
    *(f32x4*)&op[i * 4] = o;
  }
}

// ---------- launch ----------
extern "C" void kernel_launch(void* const* d_in, const int* in_sizes, int n_in,
                              void* d_out, int out_size, void* d_ws, size_t ws_size,
                              hipStream_t stream) {
  const float* x      = (const float*)d_in[0];
  const float* emb    = (const float*)d_in[1];
  const float* conv_w = (const float*)d_in[2];
  const float* conv_b = (const float*)d_in[3];
  const float* Wq = (const float*)d_in[4],  *bq = (const float*)d_in[5];
  const float* Wk = (const float*)d_in[6],  *bk = (const float*)d_in[7];
  const float* Wv = (const float*)d_in[8],  *bv = (const float*)d_in[9];
  const float* Wo = (const float*)d_in[10], *bo = (const float*)d_in[11];
  const float* ln1g = (const float*)d_in[12], *ln1b = (const float*)d_in[13];
  const float* ln2g = (const float*)d_in[14], *ln2b = (const float*)d_in[15];
  const float* W1 = (const float*)d_in[16], *b1 = (const float*)d_in[17];
  const float* W2 = (const float*)d_in[18], *b2 = (const float*)d_in[19];
  const float* res1 = (const float*)d_in[20], *res2 = (const float*)d_in[21];
  const float* lin_w = (const float*)d_in[22], *lin_b = (const float*)d_in[23];
  float* out = (float*)d_out;

  char* ws = (char*)d_ws;
  float* bias   = (float*)ws;                                        //    16,384 B
  float* hbuf   = (float*)(ws + 16384);                              // 67,108,864 B (layers)
  float* Ppart  = hbuf;                                              // overlay: GEMM partials (after layers)
  u16*   wt     = (u16*)(ws + 16384 + 67108864);                     // 134,217,728 B
  u16*   Abf    = (u16*)(ws + 16384 + 67108864 + 134217728);         // 33,554,432 B
  u16*   WTb    = (u16*)(ws + 16384 + 67108864 + 134217728 + 33554432); // 196,608 B
  u16* WqT = WTb;                 // 8192 elems (2 layers)
  u16* WkT = WTb + 8192;
  u16* WvT = WTb + 16384;
  u16* WoT = WTb + 24576;
  u16* W1T = WTb + 32768;         // 32768 elems
  u16* W2T = WTb + 65536;         // 32768 elems
  // conv transposed weights live in the dead PREFIX of Abf (k_conv runs before
  // the layers; layer-1's fused packA overwrites this region afterwards).
  float* cwT = (float*)Abf;       // 65536 f32 = 262,144 B
  float* cbT = cwT + 65536;       //  4096 f32 =  16,384 B

  k_wprep<<<657, 256, 0, stream>>>(Wq, Wk, Wv, Wo, W1, W2, conv_w, conv_b, emb,
                                   WqT, WkT, WvT, WoT, W1T, W2T, cwT, cbT, bias);
  k_conv<<<2048, 256, 0, stream>>>(x, cwT, cbT, hbuf);
  k_transpose<<<2048, 256, 0, stream>>>(lin_w, wt);
  for (int l = 0; l < 2; l++)
    k_layer2<<<4096, 256, 0, stream>>>(hbuf, emb, bias,
        WqT + l * 4096, WkT + l * 4096, WvT + l * 4096, WoT + l * 4096,
        W1T + l * 16384, W2T + l * 16384,
        bq + l * 64, bk + l * 64, bv + l * 64, bo + l * 64,
        ln1g + l * 64, ln1b + l * 64, ln2g + l * 64, ln2b + l * 64,
        b1 + l * 256, b2 + l * 64, res1 + l, res2 + l,
        (l == 1) ? Abf : (u16*)nullptr);
  k_gemm3<<<512, 256, 0, stream>>>(Abf, wt, Ppart);
  k_reduce<<<256, 256, 0, stream>>>(Ppart, lin_b, out);
}

// Round 20
// 633.531 us; speedup vs baseline: 1.1454x; 1.0038x over previous
//
#include <hip/hip_runtime.h>
#include <hip/hip_bf16.h>
#include <stdint.h>

// ---------- helpers ----------
#define AS1(p) ((const __attribute__((address_space(1))) void*)(p))
#define AS3(p) ((__attribute__((address_space(3))) void*)(p))

typedef __bf16 bf16x8 __attribute__((ext_vector_type(8)));
typedef __bf16 bf16x4 __attribute__((ext_vector_type(4)));
typedef float f32x4 __attribute__((ext_vector_type(4)));
typedef unsigned short u16;

#define MFMA(a, b, cc) __builtin_amdgcn_mfma_f32_16x16x32_bf16(a, b, cc, 0, 0, 0)
// Drain outstanding DS ops (reads included) BEFORE a barrier (r8 lesson).
#define DS_DRAIN() asm volatile("s_waitcnt lgkmcnt(0)" ::: "memory")

__device__ __forceinline__ u16 f2bf(float f) {
  unsigned u = __builtin_bit_cast(unsigned, f);
  u = (u + 0x7FFFu + ((u >> 16) & 1u)) >> 16;   // RNE
  return (u16)u;
}

// ---------- constants ----------
// B=16 L=4096 N=64 D=64 H=4 WAVE=16 T=256 DFF=256 DH=16 TOPK=16

// ---------- k_wprep: weight transposes + (block 656) cosine-topk bias ----------
__global__ void k_wprep(const float* __restrict__ Wq, const float* __restrict__ Wk,
                        const float* __restrict__ Wv, const float* __restrict__ Wo,
                        const float* __restrict__ W1, const float* __restrict__ W2,
                        const float* __restrict__ conv_w, const float* __restrict__ conv_b,
                        const float* __restrict__ emb,
                        u16* __restrict__ WqT, u16* __restrict__ WkT,
                        u16* __restrict__ WvT, u16* __restrict__ WoT,
                        u16* __restrict__ W1T, u16* __restrict__ W2T,
                        float* __restrict__ cwT, float* __restrict__ cbT,
                        float* __restrict__ bias) {
  __shared__ float sh[8320];   // e[4096] | nrm[64] | cosr[64*65] (bias block only)
  int tid = threadIdx.x;
  if (blockIdx.x == 656) {
    float* e = sh; float* nrm = sh + 4096; float* cosr = sh + 4160;
    for (int idx = tid; idx < 4096; idx += 256) e[idx] = emb[idx];
    __syncthreads();
    if (tid < 64) {
      float s = 0.f;
      for (int j = 0; j < 64; j++) { float v = e[tid * 64 + j]; s += v * v; }
      nrm[tid] = sqrtf(s);
    }
    __syncthreads();
    if (tid < 64) {
      for (int jj = 0; jj < 64; jj++) {
        float d = 0.f;
        for (int kk = 0; kk < 64; kk++) d += e[tid * 64 + kk] * e[jj * 64 + kk];
        cosr[tid * 65 + jj] = d / (nrm[tid] * nrm[jj]);
      }
      unsigned long long sel = 0ull;
      for (int it = 0; it < 16; it++) {
        float best = -1e30f; int bi = 0;
        for (int j = 0; j < 64; j++) {
          if ((sel >> j) & 1ull) continue;
          float cv = cosr[tid * 65 + j];
          if (cv > best) { best = cv; bi = j; }
        }
        sel |= (1ull << bi);
      }
      for (int j = 0; j < 64; j++)
        bias[tid * 64 + j] = ((sel >> j) & 1ull) ? 0.0f : -1e9f;
    }
    return;
  }
  int e = blockIdx.x * 256 + tid;   // 167936 total
  if (e < 98304) {
    int l = e / 49152, r = e % 49152;
    if (r < 16384) {
      int mat = r >> 12, i = r & 4095, n = i >> 6, k = i & 63;
      const float* W = mat == 0 ? Wq : mat == 1 ? Wk : mat == 2 ? Wv : Wo;
      u16* WT = mat == 0 ? WqT : mat == 1 ? WkT : mat == 2 ? WvT : WoT;
      WT[l * 4096 + i] = f2bf(W[l * 4096 + k * 64 + n]);
    } else if (r < 32768) {
      int i = r - 16384, n = i >> 6, k = i & 63;
      W1T[l * 16384 + i] = f2bf(W1[l * 16384 + k * 256 + n]);
    } else {
      int i = r - 32768, n = i >> 8, k = i & 255;
      W2T[l * 16384 + i] = f2bf(W2[l * 16384 + k * 64 + n]);
    }
  } else if (e < 163840) {
    int i = e - 98304;                       // cwT[(n*16+w)*64+d] = conv_w[(d*64+n)*16+w]
    int d = i & 63, w = (i >> 6) & 15, n = i >> 10;
    cwT[i] = conv_w[(d * 64 + n) * 16 + w];
  } else {
    int i = e - 163840;                      // cbT[n*64+d] = conv_b[d*64+n]
    int d = i & 63, n = i >> 6;
    cbT[i] = conv_b[d * 64 + n];
  }
}

// ---------- k_conv: 8 tokens x 16-n group per block; weights register-resident ----------
__global__ __launch_bounds__(256) void k_conv(const float* __restrict__ x,
                                              const float* __restrict__ cwT,
                                              const float* __restrict__ cbT,
                                              float* __restrict__ h) {
  __shared__ float xs[8192];          // 8 tokens x 1024
  const int tc = blockIdx.x >> 2;     // 512 token-chunks of 8
  const int ng = blockIdx.x & 3;      // 4 n-groups of 16
  const int tid = threadIdx.x;
  const int d = tid & 63, nsub = tid >> 6;
  #pragma unroll
  for (int i = 0; i < 8; i++)
    ((f32x4*)xs)[i * 256 + tid] = ((const f32x4*)(x + ((size_t)tc << 13)))[i * 256 + tid];
  float wv[4][16];
  float cb[4];
  #pragma unroll
  for (int i = 0; i < 4; i++) {
    int n = (ng << 4) + (nsub << 2) + i;
    cb[i] = cbT[n * 64 + d];
    #pragma unroll
    for (int w = 0; w < 16; w++) wv[i][w] = cwT[n * 1024 + w * 64 + d];
  }
  __syncthreads();
  for (int t = 0; t < 8; t++) {
    float xv[16];
    #pragma unroll
    for (int w = 0; w < 16; w++) xv[w] = xs[t * 1024 + w * 64 + d];
    #pragma unroll
    for (int i = 0; i < 4; i++) {
      int n = (ng << 4) + (nsub << 2) + i;
      float acc = cb[i];
      #pragma unroll
      for (int w = 0; w < 16; w++) acc += xv[w] * wv[i][w];
      h[(((size_t)(tc * 8 + t)) << 12) + n * 64 + d] = acc;
    }
  }
}

// ---------- k_layer2: fused MFMA transformer layer, one (b,t) per block ----------
// (r17 stable version: grid 4096, per-token prefetch, in-register softmax,
// LDS 70656 B -> 2 blocks/CU)
__global__ __launch_bounds__(256, 2) void k_layer2(
    float* __restrict__ hbuf, const float* __restrict__ emb, const float* __restrict__ bias,
    const u16* __restrict__ WqT, const u16* __restrict__ WkT,
    const u16* __restrict__ WvT, const u16* __restrict__ WoT,
    const u16* __restrict__ W1T, const u16* __restrict__ W2T,
    const float* __restrict__ bq, const float* __restrict__ bk,
    const float* __restrict__ bv, const float* __restrict__ bo,
    const float* __restrict__ ln1g, const float* __restrict__ ln1b,
    const float* __restrict__ ln2g, const float* __restrict__ ln2b,
    const float* __restrict__ b1, const float* __restrict__ b2,
    const float* __restrict__ r1p, const float* __restrict__ r2p,
    u16* __restrict__ aout) {
  __shared__ __align__(16) unsigned char smem[70656];
  float* hres = (float*)smem;                 // [64][68] f32
  __bf16* act = (__bf16*)(smem + 17408);      // [64][72]
  __bf16* qb  = (__bf16*)(smem + 26624);      // [64][136] (per-head 32-wide, hi 16 zero)
  __bf16* kb  = (__bf16*)(smem + 44032);      // [64][136]
  __bf16* vtb = (__bf16*)(smem + 61440);      // [64][72]  V^T [d][node]
  __bf16* ps  = (__bf16*)(smem + 26624);      // [64][264] P, overlays qb+kb
  __bf16* gb  = (__bf16*)(smem + 26624);      // [64][264] FFN hidden, overlays qb+kb

  const int tid = threadIdx.x;
  const int w = tid >> 6, lane = tid & 63;
  const int g = lane >> 4, c = lane & 15;
  const size_t base = (size_t)blockIdx.x << 12;
  const float r1 = *r1p, r2 = *r2p;

  // --- prefetch phase-2/4 weights + biases (latency hides under phase 1) ---
  const int wrow = (w * 16 + c) * 64 + g * 8;
  bf16x8 wq0 = *(const bf16x8*)&WqT[wrow];
  bf16x8 wq1 = *(const bf16x8*)&WqT[wrow + 32];
  bf16x8 wk0 = *(const bf16x8*)&WkT[wrow];
  bf16x8 wk1 = *(const bf16x8*)&WkT[wrow + 32];
  bf16x8 wv0 = *(const bf16x8*)&WvT[wrow];
  bf16x8 wv1 = *(const bf16x8*)&WvT[wrow + 32];
  bf16x8 wo0 = *(const bf16x8*)&WoT[wrow];
  bf16x8 wo1 = *(const bf16x8*)&WoT[wrow + 32];
  f32x4 bq4 = *(const f32x4*)&bq[w * 16 + g * 4];
  f32x4 bk4 = *(const f32x4*)&bk[w * 16 + g * 4];
  f32x4 bo4 = *(const f32x4*)&bo[w * 16 + g * 4];
  f32x4 b24 = *(const f32x4*)&b2[w * 16 + g * 4];
  float bvv = bv[w * 16 + c];

  // phase 1: load h, hin = h+emb -> act(bf16); zero qb/kb (padding lanes)
  #pragma unroll
  for (int i = 0; i < 4; i++) {
    int v = tid + (i << 8);
    f32x4 hv = ((const f32x4*)(hbuf + base))[v];
    f32x4 ev = ((const f32x4*)emb)[v];
    int n = v >> 4, d = (v & 15) << 2;
    *(f32x4*)&hres[n * 68 + d] = hv;
    bf16x4 u;
    u[0] = (__bf16)(hv[0] + ev[0]); u[1] = (__bf16)(hv[1] + ev[1]);
    u[2] = (__bf16)(hv[2] + ev[2]); u[3] = (__bf16)(hv[3] + ev[3]);
    *(bf16x4*)&act[n * 72 + d] = u;
  }
  for (int i = tid; i < 2176; i += 256) {
    f32x4 z; z[0] = 0.f; z[1] = 0.f; z[2] = 0.f; z[3] = 0.f;
    ((f32x4*)(smem + 26624))[i] = z;
  }
  __syncthreads();   // bar1

  bf16x8 af[4][2];
  auto load_af_act = [&]() {
    #pragma unroll
    for (int rt = 0; rt < 4; rt++)
      #pragma unroll
      for (int ks = 0; ks < 2; ks++)
        af[rt][ks] = *(const bf16x8*)&act[(rt * 16 + c) * 72 + ks * 32 + g * 8];
  };

  // phase 2: QKV. q/k operand-swapped (D[d][n]) -> packed stores into qb/kb[n][d];
  // v unswapped -> packed stores into vtb[d][n].
  load_af_act();
  {
    #pragma unroll
    for (int nt = 0; nt < 4; nt++) {
      f32x4 a; a[0]=0.f; a[1]=0.f; a[2]=0.f; a[3]=0.f;
      a = MFMA(wq0, af[nt][0], a);
      a = MFMA(wq1, af[nt][1], a);
      bf16x4 st;
      #pragma unroll
      for (int jj = 0; jj < 4; jj++) st[jj] = (__bf16)(a[jj] + bq4[jj]);
      *(bf16x4*)&qb[(nt * 16 + c) * 136 + w * 32 + g * 4] = st;
    }
    #pragma unroll
    for (int nt = 0; nt < 4; nt++) {
      f32x4 a; a[0]=0.f; a[1]=0.f; a[2]=0.f; a[3]=0.f;
      a = MFMA(wk0, af[nt][0], a);
      a = MFMA(wk1, af[nt][1], a);
      bf16x4 st;
      #pragma unroll
      for (int jj = 0; jj < 4; jj++) st[jj] = (__bf16)(a[jj] + bk4[jj]);
      *(bf16x4*)&kb[(nt * 16 + c) * 136 + w * 32 + g * 4] = st;
    }
    #pragma unroll
    for (int nt = 0; nt < 4; nt++) {
      f32x4 a; a[0]=0.f; a[1]=0.f; a[2]=0.f; a[3]=0.f;
      a = MFMA(af[nt][0], wv0, a);
      a = MFMA(af[nt][1], wv1, a);
      bf16x4 st;
      #pragma unroll
      for (int jj = 0; jj < 4; jj++) st[jj] = (__bf16)(a[jj] + bvv);
      *(bf16x4*)&vtb[(w * 16 + c) * 72 + nt * 16 + g * 4] = st;
    }
  }
  __syncthreads();   // bar2

  // --- prefetch FFN1 weights + biases (latency hides under attention) ---
  bf16x8 w1f[4][2];
  f32x4 b14[4];
  #pragma unroll
  for (int ft = 0; ft < 4; ft++) {
    int ffb = (w << 6) + (ft << 4);
    w1f[ft][0] = *(const bf16x8*)&W1T[(ffb + c) * 64 + g * 8];
    w1f[ft][1] = *(const bf16x8*)&W1T[(ffb + c) * 64 + 32 + g * 8];
    b14[ft] = *(const f32x4*)&b1[ffb + g * 4];
  }

  // phase 3: attention (row-split: wave w owns query rows 16w..16w+15)
  {
    float bias_r[4][4];
    #pragma unroll
    for (int jj = 0; jj < 4; jj++)
      #pragma unroll
      for (int ct = 0; ct < 4; ct++)
        bias_r[jj][ct] = bias[(w * 16 + g * 4 + jj) * 64 + ct * 16 + c];

    // Stage A: all 4 heads' QK^T into registers
    f32x4 sc4[4][4];   // [head][ct]
    #pragma unroll
    for (int h = 0; h < 4; h++) {
      bf16x8 aq = *(const bf16x8*)&qb[(w * 16 + c) * 136 + h * 32 + g * 8];
      #pragma unroll
      for (int ct = 0; ct < 4; ct++) {
        bf16x8 bk8 = *(const bf16x8*)&kb[(ct * 16 + c) * 136 + h * 32 + g * 8];
        f32x4 z0; z0[0]=0.f; z0[1]=0.f; z0[2]=0.f; z0[3]=0.f;
        sc4[h][ct] = MFMA(aq, bk8, z0);
      }
    }

    // Stage B (registers only): softmax consumes sc4 BEFORE the barrier and
    // overwrites it in place with the normalized probabilities.
    #pragma unroll
    for (int h = 0; h < 4; h++) {
      #pragma unroll
      for (int jj = 0; jj < 4; jj++) {
        float s0 = sc4[h][0][jj] * 0.25f + bias_r[jj][0];
        float s1 = sc4[h][1][jj] * 0.25f + bias_r[jj][1];
        float s2 = sc4[h][2][jj] * 0.25f + bias_r[jj][2];
        float s3 = sc4[h][3][jj] * 0.25f + bias_r[jj][3];
        float m = fmaxf(fmaxf(s0, s1), fmaxf(s2, s3));
        m = fmaxf(m, __shfl_xor(m, 1)); m = fmaxf(m, __shfl_xor(m, 2));
        m = fmaxf(m, __shfl_xor(m, 4)); m = fmaxf(m, __shfl_xor(m, 8));
        float e0 = __expf(s0 - m), e1 = __expf(s1 - m), e2 = __expf(s2 - m), e3 = __expf(s3 - m);
        float sum = e0 + e1 + e2 + e3;
        sum += __shfl_xor(sum, 1); sum += __shfl_xor(sum, 2);
        sum += __shfl_xor(sum, 4); sum += __shfl_xor(sum, 8);
        float inv = __builtin_amdgcn_rcpf(sum);
        sc4[h][0][jj] = e0 * inv;
        sc4[h][1][jj] = e1 * inv;
        sc4[h][2][jj] = e2 * inv;
        sc4[h][3][jj] = e3 * inv;
      }
    }

    DS_DRAIN();        // ensure no qb/kb read is in flight across the barrier
    __syncthreads();   // qb/kb region now dead -> becomes ps

    // Stage B'': store P (bf16) into ps
    #pragma unroll
    for (int h = 0; h < 4; h++) {
      #pragma unroll
      for (int jj = 0; jj < 4; jj++) {
        int prow = w * 16 + g * 4 + jj;
        ps[prow * 264 + h * 64 +  0 + c] = (__bf16)sc4[h][0][jj];
        ps[prow * 264 + h * 64 + 16 + c] = (__bf16)sc4[h][1][jj];
        ps[prow * 264 + h * 64 + 32 + c] = (__bf16)sc4[h][2][jj];
        ps[prow * 264 + h * 64 + 48 + c] = (__bf16)sc4[h][3][jj];
      }
    }
    __syncthreads();   // P visible

    // Stage C: PV operand-swapped (D[dh][q]) -> packed bf16x4 act stores
    #pragma unroll
    for (int h = 0; h < 4; h++) {
      f32x4 oacc; oacc[0]=0.f; oacc[1]=0.f; oacc[2]=0.f; oacc[3]=0.f;
      #pragma unroll
      for (int ks = 0; ks < 2; ks++) {
        bf16x8 ap  = *(const bf16x8*)&ps[(w * 16 + c) * 264 + h * 64 + ks * 32 + g * 8];
        bf16x8 bv8 = *(const bf16x8*)&vtb[(h * 16 + c) * 72 + ks * 32 + g * 8];
        oacc = MFMA(bv8, ap, oacc);   // A=V^T[dh][key], B=P^T[key][q]
      }
      bf16x4 st;
      #pragma unroll
      for (int jj = 0; jj < 4; jj++) st[jj] = (__bf16)oacc[jj];
      *(bf16x4*)&act[(w * 16 + c) * 72 + h * 16 + g * 4] = st;
    }
  }
  __syncthreads();   // bar3

  // phase 4: proj + residual (operand-swapped: D[d][n] -> f32x4 RMW on hres)
  load_af_act();
  {
    #pragma unroll
    for (int nt = 0; nt < 4; nt++) {
      f32x4 a; a[0]=0.f; a[1]=0.f; a[2]=0.f; a[3]=0.f;
      a = MFMA(wo0, af[nt][0], a);
      a = MFMA(wo1, af[nt][1], a);
      float* hp = &hres[(nt * 16 + c) * 68 + w * 16 + g * 4];
      f32x4 hv = *(f32x4*)hp;
      #pragma unroll
      for (int jj = 0; jj < 4; jj++) hv[jj] += r1 * (a[jj] + bo4[jj]);
      *(f32x4*)hp = hv;
    }
  }
  __syncthreads();   // bar4

  // phase 5: LN1 -> act (bf16 FFN input) AND hres (fp32 residual)
  {
    int row = w * 16 + (lane >> 2), c0 = (lane & 3) << 4;
    float s = 0.f, s2 = 0.f;
    #pragma unroll
    for (int jv = 0; jv < 4; jv++) {
      f32x4 v = *(const f32x4*)&hres[row * 68 + c0 + jv * 4];
      s += v[0] + v[1] + v[2] + v[3];
      s2 += v[0]*v[0] + v[1]*v[1] + v[2]*v[2] + v[3]*v[3];
    }
    s += __shfl_xor(s, 1);  s += __shfl_xor(s, 2);
    s2 += __shfl_xor(s2, 1); s2 += __shfl_xor(s2, 2);
    float mean = s * 0.015625f, var = s2 * 0.015625f - mean * mean;
    float rstd = rsqrtf(var + 1e-5f);
    #pragma unroll
    for (int jv = 0; jv < 4; jv++) {
      f32x4 v = *(const f32x4*)&hres[row * 68 + c0 + jv * 4];
      f32x4 gg = *(const f32x4*)&ln1g[c0 + jv * 4];
      f32x4 bb = *(const f32x4*)&ln1b[c0 + jv * 4];
      f32x4 o; bf16x4 ob;
      #pragma unroll
      for (int e = 0; e < 4; e++) {
        o[e] = (v[e] - mean) * rstd * gg[e] + bb[e];
        ob[e] = (__bf16)o[e];
      }
      *(f32x4*)&hres[row * 68 + c0 + jv * 4] = o;
      *(bf16x4*)&act[row * 72 + c0 + jv * 4] = ob;
    }
  }
  __syncthreads();   // bar5

  // phase 6: FFN1 operand-swapped (D[ff][n]); weights prefetched (w1f/b14).
  load_af_act();
  // --- prefetch FFN2 weights (latency hides under FFN1 MFMA+gelu) ---
  bf16x8 w2f[8];
  #pragma unroll
  for (int ks = 0; ks < 8; ks++)
    w2f[ks] = *(const bf16x8*)&W2T[(w * 16 + c) * 256 + ks * 32 + g * 8];
  #pragma unroll
  for (int ft = 0; ft < 4; ft++) {
    int ffb = (w << 6) + (ft << 4);
    #pragma unroll
    for (int nt = 0; nt < 4; nt++) {
      f32x4 a; a[0]=0.f; a[1]=0.f; a[2]=0.f; a[3]=0.f;
      a = MFMA(w1f[ft][0], af[nt][0], a);
      a = MFMA(w1f[ft][1], af[nt][1], a);
      bf16x4 st;
      #pragma unroll
      for (int jj = 0; jj < 4; jj++) {
        float xg = a[jj] + b14[ft][jj];
        float e = __expf(1.5957691216057308f * (xg + 0.044715f * xg * xg * xg));
        float r = __builtin_amdgcn_rcpf(1.f + e);
        st[jj] = (__bf16)(xg - xg * r);
      }
      *(bf16x4*)&gb[(nt * 16 + c) * 264 + ffb + g * 4] = st;
    }
  }
  __syncthreads();   // bar6

  // phase 7: FFN2 + residual (operand-swapped: D[d][n] -> f32x4 RMW on hres)
  {
    f32x4 a2[4];
    #pragma unroll
    for (int nt = 0; nt < 4; nt++) { a2[nt][0]=0.f; a2[nt][1]=0.f; a2[nt][2]=0.f; a2[nt][3]=0.f; }
    #pragma unroll
    for (int ks = 0; ks < 8; ks++) {
      #pragma unroll
      for (int nt = 0; nt < 4; nt++) {
        bf16x8 ag = *(const bf16x8*)&gb[(nt * 16 + c) * 264 + ks * 32 + g * 8];
        a2[nt] = MFMA(w2f[ks], ag, a2[nt]);
      }
    }
    #pragma unroll
    for (int nt = 0; nt < 4; nt++) {
      float* hp = &hres[(nt * 16 + c) * 68 + w * 16 + g * 4];
      f32x4 hv = *(f32x4*)hp;
      #pragma unroll
      for (int jj = 0; jj < 4; jj++) hv[jj] += r2 * (a2[nt][jj] + b24[jj]);
      *(f32x4*)hp = hv;
    }
  }
  __syncthreads();   // bar7

  // phase 8: LN2 -> hbuf (fp32) or fused packA -> aout (bf16 GEMM A)
  {
    int row = w * 16 + (lane >> 2), c0 = (lane & 3) << 4;
    float s = 0.f, s2 = 0.f;
    #pragma unroll
    for (int jv = 0; jv < 4; jv++) {
      f32x4 v = *(const f32x4*)&hres[row * 68 + c0 + jv * 4];
      s += v[0] + v[1] + v[2] + v[3];
      s2 += v[0]*v[0] + v[1]*v[1] + v[2]*v[2] + v[3]*v[3];
    }
    s += __shfl_xor(s, 1);  s += __shfl_xor(s, 2);
    s2 += __shfl_xor(s2, 1); s2 += __shfl_xor(s2, 2);
    float mean = s * 0.015625f, var = s2 * 0.015625f - mean * mean;
    float rstd = rsqrtf(var + 1e-5f);
    if (aout) {
      int b = (int)(blockIdx.x >> 8), t = (int)(blockIdx.x & 255);
      __bf16* ao = (__bf16*)aout + (((size_t)(b * 64 + row)) << 14) + (t << 6) + c0;
      #pragma unroll
      for (int jv = 0; jv < 4; jv++) {
        f32x4 v = *(const f32x4*)&hres[row * 68 + c0 + jv * 4];
        f32x4 gg = *(const f32x4*)&ln2g[c0 + jv * 4];
        f32x4 bb = *(const f32x4*)&ln2b[c0 + jv * 4];
        bf16x4 us;
        #pragma unroll
        for (int e = 0; e < 4; e++)
          us[e] = (__bf16)((v[e] - mean) * rstd * gg[e] + bb[e]);
        *(bf16x4*)&ao[jv * 4] = us;
      }
    } else {
      #pragma unroll
      for (int jv = 0; jv < 4; jv++) {
        f32x4 v = *(const f32x4*)&hres[row * 68 + c0 + jv * 4];
        f32x4 gg = *(const f32x4*)&ln2g[c0 + jv * 4];
        f32x4 bb = *(const f32x4*)&ln2b[c0 + jv * 4];
        f32x4 o;
        #pragma unroll
        for (int e = 0; e < 4; e++)
          o[e] = (v[e] - mean) * rstd * gg[e] + bb[e];
        *(f32x4*)&hbuf[base + row * 64 + c0 + jv * 4] = o;
      }
    }
  }
}

// ---------- k_transpose: lin_w [16384][4096] f32 -> wt [4096][16384] bf16 ----------
__global__ __launch_bounds__(256) void k_transpose(const float* __restrict__ w,
                                                   u16* __restrict__ wt) {
  __shared__ u16 tb[128 * 256];   // 64 KB
  const int bn = blockIdx.x & 15;   // 16 n-tiles of 256
  const int bk = blockIdx.x >> 4;   // 128 k-tiles of 128
  const int tid = threadIdx.x;
  #pragma unroll
  for (int i = 0; i < 32; i++) {
    int chunk = i * 256 + tid;
    int row = chunk >> 6, cq = chunk & 63;
    f32x4 v = *(const f32x4*)&w[((size_t)(bk * 128 + row)) * 4096 + bn * 256 + cq * 4];
    ushort4 u;
    u.x = f2bf(v[0]); u.y = f2bf(v[1]); u.z = f2bf(v[2]); u.w = f2bf(v[3]);
    int pc = cq ^ ((row >> 2) & 15);
    *(ushort4*)&tb[row * 256 + pc * 4] = u;
  }
  __syncthreads();
  #pragma unroll
  for (int i = 0; i < 32; i++) {
    int chunk = i * 256 + tid;
    int n = chunk >> 5, kq = chunk & 31;
    int pc = (n >> 2) ^ (kq & 15);
    int nl = n & 3;
    ushort4 u;
    u.x = tb[(kq * 4 + 0) * 256 + pc * 4 + nl];
    u.y = tb[(kq * 4 + 1) * 256 + pc * 4 + nl];
    u.z = tb[(kq * 4 + 2) * 256 + pc * 4 + nl];
    u.w = tb[(kq * 4 + 3) * 256 + pc * 4 + nl];
    *(ushort4*)&wt[((size_t)(bn * 256 + n)) * 16384 + bk * 128 + kq * 4] = u;
  }
}

// ---------- k_gemm3: 256x128 tile, K-split x4, 512 blocks, XOR-swizzled LDS ----------
__global__ __launch_bounds__(256, 2) void k_gemm3(const u16* __restrict__ A,
                                                  const u16* __restrict__ Bt,
                                                  float* __restrict__ P) {
  __shared__ u16 As[256 * 64];   // 32 KB
  __shared__ u16 Bs[128 * 64];   // 16 KB
  const int tid = threadIdx.x;
  const int lane = tid & 63;
  const int wv = tid >> 6;
  const int bid = ((blockIdx.x & 7) << 6) | (blockIdx.x >> 3);
  const int split = bid >> 7;
  const int tile = bid & 127;
  const int bm = tile >> 5, bn = tile & 31;
  const int m0 = bm << 8, n0 = bn << 7;
  f32x4 acc[4][8];
  #pragma unroll
  for (int i = 0; i < 4; i++)
    #pragma unroll
    for (int j = 0; j < 8; j++) { acc[i][j][0]=0.f; acc[i][j][1]=0.f; acc[i][j][2]=0.f; acc[i][j][3]=0.f; }

  const int r15 = lane & 15;
  const int g = lane >> 4;
  const u16* abase = A  + ((size_t)m0 << 14) + (split << 12);
  const u16* bbase = Bt + ((size_t)n0 << 14) + (split << 12);

  for (int kt = 0; kt < 64; kt++) {
    const u16* ab = abase + (kt << 6);
    const u16* bb = bbase + (kt << 6);
    #pragma unroll
    for (int j = 0; j < 8; j++) {
      int cix = (j << 8) + tid;
      int row = cix >> 3;
      int sc  = (cix & 7) ^ (row & 7);
      int off = (row << 14) + (sc << 3);
      __builtin_amdgcn_global_load_lds(AS1(ab + off), AS3(&As[(j << 11) + (wv << 9)]), 16, 0, 0);
    }
    #pragma unroll
    for (int j = 0; j < 4; j++) {
      int cix = (j << 8) + tid;
      int row = cix >> 3;
      int sc  = (cix & 7) ^ (row & 7);
      int off = (row << 14) + (sc << 3);
      __builtin_amdgcn_global_load_lds(AS1(bb + off), AS3(&Bs[(j << 11) + (wv << 9)]), 16, 0, 0);
    }
    __syncthreads();
    #pragma unroll
    for (int ks = 0; ks < 2; ks++) {
      const int pc = ((ks << 2) + g) ^ (r15 & 7);
      bf16x8 af2[4], bfr[8];
      #pragma unroll
      for (int mi = 0; mi < 4; mi++)
        af2[mi] = *(const bf16x8*)&As[((wv << 6) + mi * 16 + r15) * 64 + (pc << 3)];
      #pragma unroll
      for (int ni = 0; ni < 8; ni++)
        bfr[ni] = *(const bf16x8*)&Bs[(ni * 16 + r15) * 64 + (pc << 3)];
      #pragma unroll
      for (int mi = 0; mi < 4; mi++)
        #pragma unroll
        for (int ni = 0; ni < 8; ni++)
          acc[mi][ni] = MFMA(af2[mi], bfr[ni], acc[mi][ni]);
    }
    __syncthreads();
  }

  float* Pp = P + ((size_t)split << 22);
  #pragma unroll
  for (int mi = 0; mi < 4; mi++) {
    #pragma unroll
    for (int ni = 0; ni < 8; ni++) {
      int col = n0 + ni * 16 + r15;
      #pragma unroll
      for (int j = 0; j < 4; j++) {
        int row = m0 + (wv << 6) + mi * 16 + (g << 2) + j;
        Pp[((size_t)row << 12) + col] = acc[mi][ni][j];
      }
    }
  }
}

// ---------- k_reduce: sum 4 K-splits + bias -> out[b,l,n] ----------
__global__ __launch_bounds__(256) void k_reduce(const float* __restrict__ P,
                                                const float* __restrict__ lin_b,
                                                float* __restrict__ out) {
  __shared__ float acc[64 * 256];   // 64 KB
  const int b = blockIdx.x >> 4;    // 16 batches
  const int lc = blockIdx.x & 15;   // 16 l-chunks of 256
  const int tid = threadIdx.x;
  const int lq = tid & 63;          // l' quad (x4)
  const int nr = tid >> 6;          // n-row group
  const float* Pb = P + (((size_t)(b * 64)) << 12) + (lc << 8);
  #pragma unroll
  for (int i = 0; i < 16; i++) {
    int n = (nr << 4) + i;
    f32x4 v = *(const f32x4*)&Pb[((size_t)n << 12) + (lq << 2)];
    *(f32x4*)&acc[n * 256 + (lq << 2)] = v;
  }
  #pragma unroll
  for (int s = 1; s < 4; s++) {
    const float* Ps = Pb + ((size_t)s << 22);
    #pragma unroll
    for (int i = 0; i < 16; i++) {
      int n = (nr << 4) + i;
      f32x4 v = *(const f32x4*)&Ps[((size_t)n << 12) + (lq << 2)];
      f32x4 a = *(f32x4*)&acc[n * 256 + (lq << 2)];
      a[0] += v[0]; a[1] += v[1]; a[2] += v[2]; a[3] += v[3];
      *(f32x4*)&acc[n * 256 + (lq << 2)] = a;
    }
  }
  __syncthreads();
  float lb = lin_b[(lc << 8) + tid];
  float* op = out + (((size_t)(b * 4096 + (lc << 8) + tid)) << 6);
  #pragma unroll
  for (int i = 0; i < 16; i++) {
    f32x4 o;
    #pragma unroll
    for (int j = 0; j < 4; j++) o[j] = acc[(i * 4 + j) * 256 + tid] + lb;
    *(f32x4*)&op[i * 4] = o;
  }
}

// ---------- launch ----------
extern "C" void kernel_launch(void* const* d_in, const int* in_sizes, int n_in,
                              void* d_out, int out_size, void* d_ws, size_t ws_size,
                              hipStream_t stream) {
  const float* x      = (const float*)d_in[0];
  const float* emb    = (const float*)d_in[1];
  const float* conv_w = (const float*)d_in[2];
  const float* conv_b = (const float*)d_in[3];
  const float* Wq = (const float*)d_in[4],  *bq = (const float*)d_in[5];
  const float* Wk = (const float*)d_in[6],  *bk = (const float*)d_in[7];
  const float* Wv = (const float*)d_in[8],  *bv = (const float*)d_in[9];
  const float* Wo = (const float*)d_in[10], *bo = (const float*)d_in[11];
  const float* ln1g = (const float*)d_in[12], *ln1b = (const float*)d_in[13];
  const float* ln2g = (const float*)d_in[14], *ln2b = (const float*)d_in[15];
  const float* W1 = (const float*)d_in[16], *b1 = (const float*)d_in[17];
  const float* W2 = (const float*)d_in[18], *b2 = (const float*)d_in[19];
  const float* res1 = (const float*)d_in[20], *res2 = (const float*)d_in[21];
  const float* lin_w = (const float*)d_in[22], *lin_b = (const float*)d_in[23];
  float* out = (float*)d_out;

  char* ws = (char*)d_ws;
  float* bias   = (float*)ws;                                        //    16,384 B
  float* hbuf   = (float*)(ws + 16384);                              // 67,108,864 B (layers)
  float* Ppart  = hbuf;                                              // overlay: GEMM partials (after layers)
  u16*   wt     = (u16*)(ws + 16384 + 67108864);                     // 134,217,728 B
  u16*   Abf    = (u16*)(ws + 16384 + 67108864 + 134217728);         // 33,554,432 B
  u16*   WTb    = (u16*)(ws + 16384 + 67108864 + 134217728 + 33554432); // 196,608 B
  u16* WqT = WTb;                 // 8192 elems (2 layers)
  u16* WkT = WTb + 8192;
  u16* WvT = WTb + 16384;
  u16* WoT = WTb + 24576;
  u16* W1T = WTb + 32768;         // 32768 elems
  u16* W2T = WTb + 65536;         // 32768 elems
  // conv transposed weights live in the dead PREFIX of Abf (k_conv runs before
  // the layers; layer-1's fused packA overwrites this region afterwards).
  float* cwT = (float*)Abf;       // 65536 f32 = 262,144 B
  float* cbT = cwT + 65536;       //  4096 f32 =  16,384 B

  k_wprep<<<657, 256, 0, stream>>>(Wq, Wk, Wv, Wo, W1, W2, conv_w, conv_b, emb,
                                   WqT, WkT, WvT, WoT, W1T, W2T, cwT, cbT, bias);
  k_conv<<<2048, 256, 0, stream>>>(x, cwT, cbT, hbuf);
  k_transpose<<<2048, 256, 0, stream>>>(lin_w, wt);
  for (int l = 0; l < 2; l++)
    k_layer2<<<4096, 256, 0, stream>>>(hbuf, emb, bias,
        WqT + l * 4096, WkT + l * 4096, WvT + l * 4096, WoT + l * 4096,
        W1T + l * 16384, W2T + l * 16384,
        bq + l * 64, bk + l * 64, bv + l * 64, bo + l * 64,
        ln1g + l * 64, ln1b + l * 64, ln2g + l * 64, ln2b + l * 64,
        b1 + l * 256, b2 + l * 64, res1 + l, res2 + l,
        (l == 1) ? Abf : (u16*)nullptr);
  k_gemm3<<<512, 256, 0, stream>>>(Abf, wt, Ppart);
  k_reduce<<<256, 256, 0, stream>>>(Ppart, lin_b, out);
}